// Round 1
// baseline (5187.584 us; speedup 1.0000x reference)
//
#include <hip/hip_runtime.h>
#include <hip/hip_bf16.h>

typedef __attribute__((ext_vector_type(8))) __bf16 bf16x8;
typedef __attribute__((ext_vector_type(4))) float floatx4;

static constexpr int S = 2048;
static constexpr int D = 2048;
static constexpr int HD = 256;
static constexpr int NH = 8;
static constexpr int NKV = 4;
static constexpr int NLAYER = 4;
static constexpr int VOCAB = 32000;
static constexpr int FF = 8192;
static constexpr int WINDOW = 1024;

// ---------------- block reduction helpers (256 threads = 4 waves) ----------------
__device__ __forceinline__ float blk_sum(float v) {
    __shared__ float sm[4];
    #pragma unroll
    for (int o = 32; o > 0; o >>= 1) v += __shfl_down(v, o, 64);
    int lane = threadIdx.x & 63, w = threadIdx.x >> 6;
    __syncthreads();
    if (lane == 0) sm[w] = v;
    __syncthreads();
    return sm[0] + sm[1] + sm[2] + sm[3];
}

__device__ __forceinline__ float blk_max(float v) {
    __shared__ float sm[4];
    #pragma unroll
    for (int o = 32; o > 0; o >>= 1) v = fmaxf(v, __shfl_down(v, o, 64));
    int lane = threadIdx.x & 63, w = threadIdx.x >> 6;
    __syncthreads();
    if (lane == 0) sm[w] = v;
    __syncthreads();
    return fmaxf(fmaxf(sm[0], sm[1]), fmaxf(sm[2], sm[3]));
}

// ---------------- elementwise kernels ----------------
__global__ void embed_kernel(const int* __restrict__ ids, const float* __restrict__ E,
                             float* __restrict__ h) {
    int d = blockIdx.x * 256 + threadIdx.x;
    int s = blockIdx.y;
    h[(long)s * D + d] = E[(long)ids[s] * D + d] * 45.25483399593904f; // sqrt(2048)
}

__global__ void rope_table_kernel(float* __restrict__ c, float* __restrict__ sn) {
    int i = threadIdx.x;   // 0..127
    int p = blockIdx.x;    // 0..S-1
    float inv = powf(10000.f, -(float)i / 128.f);
    float a = (float)p * inv;
    c[p * 128 + i] = cosf(a);
    sn[p * 128 + i] = sinf(a);
}

// x = rms(h, w) -> bf16
__global__ void rms_bf16_kernel(const float* __restrict__ h, const float* __restrict__ w,
                                __hip_bfloat16* __restrict__ o) {
    int s = blockIdx.x;
    const float* row = h + (long)s * D;
    float vals[8], ss = 0.f;
    #pragma unroll
    for (int t = 0; t < 8; ++t) {
        int j = t * 256 + threadIdx.x;
        float v = row[j]; vals[t] = v; ss += v * v;
    }
    ss = blk_sum(ss);
    float r = rsqrtf(ss * (1.f / D) + 1e-6f);
    #pragma unroll
    for (int t = 0; t < 8; ++t) {
        int j = t * 256 + threadIdx.x;
        o[(long)s * D + j] = __float2bfloat16(vals[t] * r * (1.f + w[j]));
    }
}

// h += rms(t, w)
__global__ void resid_rms_kernel(float* __restrict__ h, const float* __restrict__ tt,
                                 const float* __restrict__ w) {
    int s = blockIdx.x;
    const float* row = tt + (long)s * D;
    float* hr = h + (long)s * D;
    float vals[8], ss = 0.f;
    #pragma unroll
    for (int t = 0; t < 8; ++t) {
        int j = t * 256 + threadIdx.x;
        float v = row[j]; vals[t] = v; ss += v * v;
    }
    ss = blk_sum(ss);
    float r = rsqrtf(ss * (1.f / D) + 1e-6f);
    #pragma unroll
    for (int t = 0; t < 8; ++t) {
        int j = t * 256 + threadIdx.x;
        hr[j] += vals[t] * r * (1.f + w[j]);
    }
}

// in-place RoPE on (S, H, 256) bf16; 128 threads per (s, head)
__global__ void rope_kernel(__hip_bfloat16* __restrict__ x, const float* __restrict__ cb,
                            const float* __restrict__ sb, int H) {
    int s = blockIdx.x, hh = blockIdx.y, i = threadIdx.x; // i in 0..127
    __hip_bfloat16* p = x + ((long)s * H + hh) * HD;
    float x1 = __bfloat162float(p[i]);
    float x2 = __bfloat162float(p[128 + i]);
    float c = cb[s * 128 + i], sn = sb[s * 128 + i];
    p[i]       = __float2bfloat16(x1 * c - x2 * sn);
    p[128 + i] = __float2bfloat16(x1 * sn + x2 * c);
}

// v (S, NKV*HD) bf16 -> vT (NKV, HD, S) bf16
__global__ void transpose_v_kernel(const __hip_bfloat16* __restrict__ v,
                                   __hip_bfloat16* __restrict__ vt) {
    __shared__ ushort tile[64][65];
    int s0 = blockIdx.x * 64, d0 = blockIdx.y * 64, kv = blockIdx.z;
    const ushort* vin = (const ushort*)v;
    ushort* vout = (ushort*)vt;
    #pragma unroll
    for (int it = 0; it < 4; ++it) {
        int slot = it * 256 + threadIdx.x;
        int r = slot >> 4, c4 = (slot & 15) << 2;
        ushort4 x = *(const ushort4*)(vin + (long)(s0 + r) * (NKV * HD) + kv * HD + d0 + c4);
        tile[r][c4] = x.x; tile[r][c4 + 1] = x.y; tile[r][c4 + 2] = x.z; tile[r][c4 + 3] = x.w;
    }
    __syncthreads();
    #pragma unroll
    for (int it = 0; it < 4; ++it) {
        int slot = it * 256 + threadIdx.x;
        int rr = slot >> 4, c4 = (slot & 15) << 2;
        ushort4 y;
        y.x = tile[c4][rr]; y.y = tile[c4 + 1][rr]; y.z = tile[c4 + 2][rr]; y.w = tile[c4 + 3][rr];
        *(ushort4*)(vout + (long)kv * HD * S + (long)(d0 + rr) * S + s0 + c4) = y;
    }
}

// scores (NH,S,S) f32 -> probs bf16, with scale, tanh softcap, mask, softmax
__global__ void softmax_kernel(const float* __restrict__ sc, __hip_bfloat16* __restrict__ pr,
                               int isLocal) {
    int i = blockIdx.x, hh = blockIdx.y;
    const float* row = sc + ((long)hh * S + i) * S;
    __hip_bfloat16* orow = pr + ((long)hh * S + i) * S;
    float vals[8];
    float m = -3.0e38f;
    #pragma unroll
    for (int t = 0; t < 8; ++t) {
        int j = t * 256 + threadIdx.x;
        bool valid = (j <= i) && (!isLocal || (i - j) < WINDOW);
        float v = tanhf(row[j] * (0.0625f / 50.f)) * 50.f; // SCALE=1/16, softcap 50
        vals[t] = valid ? v : -3.0e38f;
        m = fmaxf(m, vals[t]);
    }
    m = blk_max(m);
    float ps[8], ssum = 0.f;
    #pragma unroll
    for (int t = 0; t < 8; ++t) {
        float p = (vals[t] > -1.0e38f) ? __expf(vals[t] - m) : 0.f;
        ps[t] = p; ssum += p;
    }
    ssum = blk_sum(ssum);
    float inv = 1.f / ssum;
    #pragma unroll
    for (int t = 0; t < 8; ++t) {
        int j = t * 256 + threadIdx.x;
        orow[j] = __float2bfloat16(ps[t] * inv);
    }
}

// gate *= up (bf16, gelu already applied to gate by GEMM epilogue)
__global__ void mul_bf16_kernel(__hip_bfloat16* __restrict__ g,
                                const __hip_bfloat16* __restrict__ u) {
    long i = ((long)blockIdx.x * 256 + threadIdx.x) * 8;
    uint4 gv = *(const uint4*)(g + i);
    uint4 uv = *(const uint4*)(u + i);
    const __hip_bfloat16* gp = (const __hip_bfloat16*)&gv;
    const __hip_bfloat16* up = (const __hip_bfloat16*)&uv;
    __hip_bfloat16 o[8];
    #pragma unroll
    for (int j = 0; j < 8; ++j)
        o[j] = __float2bfloat16(__bfloat162float(gp[j]) * __bfloat162float(up[j]));
    *(uint4*)(g + i) = *(const uint4*)o;
}

// ---------------- GEMM: C[M,N] = A[M,K] * B[N,K]^T  (NT, K contiguous both sides) ----------------
// BDT: 0 = B is fp32 (converted during staging), 1 = B is bf16
// EPI: 0 = f32 store, 1 = bf16 store, 2 = gelu(tanh)->bf16, 3 = tanh(x/30)*30 -> f32
template<int BDT, int EPI>
__global__ __launch_bounds__(256) void gemm_nt_kernel(
    const __hip_bfloat16* __restrict__ A, const void* __restrict__ Bv,
    void* __restrict__ Cv, int K, int lda, int ldb, int ldc,
    long aBatch, long bBatch, long cBatch, int bzDiv) {
    __shared__ __hip_bfloat16 As[128][32];
    __shared__ __hip_bfloat16 Bs[128][32];
    const int tid = threadIdx.x;
    const int bz = blockIdx.z;
    const __hip_bfloat16* Ab = A + (long)bz * aBatch + (long)blockIdx.x * 128 * lda;
    const long bOff = (long)(bz / bzDiv) * bBatch + (long)blockIdx.y * 128 * ldb;

    const int wid = tid >> 6, lane = tid & 63;
    const int wr = (wid >> 1) * 64, wc = (wid & 1) * 64;
    const int fr = lane & 15;        // fragment row/col (lane&15)
    const int kb = (lane >> 4) * 8;  // k sub-block

    floatx4 acc[4][4] = {};

    for (int k0 = 0; k0 < K; k0 += 32) {
        __syncthreads();
        // stage A (bf16): 128x32, 16B per thread-slot
        #pragma unroll
        for (int it = 0; it < 2; ++it) {
            int slot = tid + it * 256;
            int r = slot >> 2, c8 = (slot & 3) * 8;
            *reinterpret_cast<uint4*>(&As[r][c8]) =
                *reinterpret_cast<const uint4*>(Ab + (long)r * lda + k0 + c8);
        }
        if constexpr (BDT == 0) {
            const float* Bp = (const float*)Bv + bOff;
            #pragma unroll
            for (int it = 0; it < 4; ++it) {
                int slot = tid + it * 256;
                int r = slot >> 3, c4 = (slot & 7) * 4;
                float4 f = *reinterpret_cast<const float4*>(Bp + (long)r * ldb + k0 + c4);
                __hip_bfloat16 t4[4] = {__float2bfloat16(f.x), __float2bfloat16(f.y),
                                        __float2bfloat16(f.z), __float2bfloat16(f.w)};
                *reinterpret_cast<ushort4*>(&Bs[r][c4]) = *reinterpret_cast<const ushort4*>(t4);
            }
        } else {
            const __hip_bfloat16* Bp = (const __hip_bfloat16*)Bv + bOff;
            #pragma unroll
            for (int it = 0; it < 2; ++it) {
                int slot = tid + it * 256;
                int r = slot >> 2, c8 = (slot & 3) * 8;
                *reinterpret_cast<uint4*>(&Bs[r][c8]) =
                    *reinterpret_cast<const uint4*>(Bp + (long)r * ldb + k0 + c8);
            }
        }
        __syncthreads();
        bf16x8 af[4], bfr[4];
        #pragma unroll
        for (int i = 0; i < 4; ++i)
            af[i] = *reinterpret_cast<const bf16x8*>(&As[wr + i * 16 + fr][kb]);
        #pragma unroll
        for (int j = 0; j < 4; ++j)
            bfr[j] = *reinterpret_cast<const bf16x8*>(&Bs[wc + j * 16 + fr][kb]);
        #pragma unroll
        for (int i = 0; i < 4; ++i) {
            #pragma unroll
            for (int j = 0; j < 4; ++j)
                acc[i][j] = __builtin_amdgcn_mfma_f32_16x16x32_bf16(af[i], bfr[j], acc[i][j], 0, 0, 0);
        }
    }

    // epilogue: C row = (lane>>4)*4+r, col = lane&15 within each 16x16 fragment
    const long cTile = (long)bz * cBatch + (long)blockIdx.x * 128 * ldc + (long)blockIdx.y * 128;
    const int rg = (lane >> 4) * 4;
    #pragma unroll
    for (int i = 0; i < 4; ++i) {
        #pragma unroll
        for (int j = 0; j < 4; ++j) {
            #pragma unroll
            for (int r = 0; r < 4; ++r) {
                int row = wr + i * 16 + rg + r;
                int col = wc + j * 16 + fr;
                long idx = cTile + (long)row * ldc + col;
                float v = acc[i][j][r];
                if constexpr (EPI == 0) {
                    ((float*)Cv)[idx] = v;
                } else if constexpr (EPI == 1) {
                    ((__hip_bfloat16*)Cv)[idx] = __float2bfloat16(v);
                } else if constexpr (EPI == 2) {
                    float g = 0.5f * v * (1.f + tanhf(0.7978845608f * (v + 0.044715f * v * v * v)));
                    ((__hip_bfloat16*)Cv)[idx] = __float2bfloat16(g);
                } else {
                    ((float*)Cv)[idx] = tanhf(v * (1.f / 30.f)) * 30.f;
                }
            }
        }
    }
}

// ---------------- host ----------------
extern "C" void kernel_launch(void* const* d_in, const int* in_sizes, int n_in,
                              void* d_out, int out_size, void* d_ws, size_t ws_size,
                              hipStream_t stream) {
    const int*   ids    = (const int*)d_in[0];
    const float* embedW = (const float*)d_in[1];
    const float* wq     = (const float*)d_in[2];
    const float* wk     = (const float*)d_in[3];
    const float* wv     = (const float*)d_in[4];
    const float* wo     = (const float*)d_in[5];
    const float* wg     = (const float*)d_in[6];
    const float* wu     = (const float*)d_in[7];
    const float* wd     = (const float*)d_in[8];
    const float* ln_in  = (const float*)d_in[9];
    const float* ln_pa  = (const float*)d_in[10];
    const float* ln_pf  = (const float*)d_in[11];
    const float* ln_pff = (const float*)d_in[12];
    const float* ln_f   = (const float*)d_in[13];
    const float* w_lm   = (const float*)d_in[14];
    float* out = (float*)d_out;

    char* ws = (char*)d_ws;
    size_t off = 0;
    auto alloc = [&](size_t bytes) -> void* {
        size_t o = (off + 255) & ~(size_t)255;
        off = o + bytes;
        return (void*)(ws + o);
    };

    float* h            = (float*)alloc((size_t)S * D * 4);
    __hip_bfloat16* xb  = (__hip_bfloat16*)alloc((size_t)S * D * 2);
    __hip_bfloat16* qb  = (__hip_bfloat16*)alloc((size_t)S * NH * HD * 2);
    __hip_bfloat16* kb  = (__hip_bfloat16*)alloc((size_t)S * NKV * HD * 2);
    __hip_bfloat16* vb  = (__hip_bfloat16*)alloc((size_t)S * NKV * HD * 2);
    __hip_bfloat16* vT  = (__hip_bfloat16*)alloc((size_t)NKV * HD * S * 2);
    __hip_bfloat16* ab  = (__hip_bfloat16*)alloc((size_t)S * NH * HD * 2);
    float* tmpf         = (float*)alloc((size_t)S * D * 4);
    __hip_bfloat16* gateb = (__hip_bfloat16*)alloc((size_t)S * FF * 2);
    __hip_bfloat16* upb   = (__hip_bfloat16*)alloc((size_t)S * FF * 2);
    float* cosb         = (float*)alloc((size_t)S * 128 * 4);
    float* sinb         = (float*)alloc((size_t)S * 128 * 4);
    float* scores       = (float*)alloc((size_t)NH * S * S * 4);
    __hip_bfloat16* probs = (__hip_bfloat16*)alloc((size_t)NH * S * S * 2);
    (void)ws_size; (void)in_sizes; (void)n_in; (void)out_size;

    rope_table_kernel<<<dim3(S), dim3(128), 0, stream>>>(cosb, sinb);
    embed_kernel<<<dim3(D / 256, S), dim3(256), 0, stream>>>(ids, embedW, h);

    const size_t SLq = (size_t)D * (NH * HD);    // 2048*2048
    const size_t SLkv = (size_t)D * (NKV * HD);  // 1024*2048
    const size_t SLff = (size_t)FF * D;          // 8192*2048

    for (int l = 0; l < NLAYER; ++l) {
        int isLocal = (l % 2 == 0) ? 1 : 0;
        // x = rms(h, ln_in)
        rms_bf16_kernel<<<dim3(S), dim3(256), 0, stream>>>(h, ln_in + l * D, xb);
        // q,k,v projections
        gemm_nt_kernel<0, 1><<<dim3(16, 16, 1), 256, 0, stream>>>(
            xb, wq + l * SLq, qb, D, D, D, NH * HD, 0, 0, 0, 1);
        gemm_nt_kernel<0, 1><<<dim3(16, 8, 1), 256, 0, stream>>>(
            xb, wk + l * SLkv, kb, D, D, D, NKV * HD, 0, 0, 0, 1);
        gemm_nt_kernel<0, 1><<<dim3(16, 8, 1), 256, 0, stream>>>(
            xb, wv + l * SLkv, vb, D, D, D, NKV * HD, 0, 0, 0, 1);
        // rope q, k
        rope_kernel<<<dim3(S, NH), dim3(128), 0, stream>>>(qb, cosb, sinb, NH);
        rope_kernel<<<dim3(S, NKV), dim3(128), 0, stream>>>(kb, cosb, sinb, NKV);
        // vT
        transpose_v_kernel<<<dim3(S / 64, HD / 64, NKV), 256, 0, stream>>>(vb, vT);
        // scores = q @ k^T per head
        gemm_nt_kernel<1, 0><<<dim3(16, 16, NH), 256, 0, stream>>>(
            qb, kb, scores, HD, NH * HD, NKV * HD, S,
            (long)HD, (long)HD, (long)S * S, 2);
        // softmax with softcap + mask
        softmax_kernel<<<dim3(S, NH), dim3(256), 0, stream>>>(scores, probs, isLocal);
        // a = probs @ v  (B = vT, NT layout)
        gemm_nt_kernel<1, 1><<<dim3(16, HD / 128, NH), 256, 0, stream>>>(
            probs, vT, ab, S, S, S, NH * HD,
            (long)S * S, (long)HD * S, (long)HD, 2);
        // attn_out = a @ wo^T
        gemm_nt_kernel<0, 0><<<dim3(16, 16, 1), 256, 0, stream>>>(
            ab, wo + l * SLq, tmpf, NH * HD, NH * HD, NH * HD, D, 0, 0, 0, 1);
        resid_rms_kernel<<<dim3(S), dim3(256), 0, stream>>>(h, tmpf, ln_pa + l * D);
        // MLP
        rms_bf16_kernel<<<dim3(S), dim3(256), 0, stream>>>(h, ln_pf + l * D, xb);
        gemm_nt_kernel<0, 2><<<dim3(16, FF / 128, 1), 256, 0, stream>>>(
            xb, wg + l * SLff, gateb, D, D, D, FF, 0, 0, 0, 1);
        gemm_nt_kernel<0, 1><<<dim3(16, FF / 128, 1), 256, 0, stream>>>(
            xb, wu + l * SLff, upb, D, D, D, FF, 0, 0, 0, 1);
        mul_bf16_kernel<<<dim3((S * FF) / (256 * 8)), 256, 0, stream>>>(gateb, upb);
        gemm_nt_kernel<0, 0><<<dim3(16, 16, 1), 256, 0, stream>>>(
            gateb, wd + l * SLff, tmpf, FF, FF, FF, D, 0, 0, 0, 1);
        resid_rms_kernel<<<dim3(S), dim3(256), 0, stream>>>(h, tmpf, ln_pff + l * D);
    }

    // final norm + LM head with tanh cap
    rms_bf16_kernel<<<dim3(S), dim3(256), 0, stream>>>(h, ln_f, xb);
    gemm_nt_kernel<0, 3><<<dim3(16, VOCAB / 128, 1), 256, 0, stream>>>(
        xb, w_lm, out, D, D, D, VOCAB, 0, 0, 0, 1);
}

// Round 2
// 4428.190 us; speedup vs baseline: 1.1715x; 1.1715x over previous
//
#include <hip/hip_runtime.h>
#include <hip/hip_bf16.h>

typedef __attribute__((ext_vector_type(8))) __bf16 bf16x8;
typedef __attribute__((ext_vector_type(4))) float floatx4;

typedef __attribute__((address_space(1))) const unsigned char kGlb;
typedef __attribute__((address_space(3))) unsigned char kLds;

static constexpr int S = 2048;
static constexpr int D = 2048;
static constexpr int HD = 256;
static constexpr int NH = 8;
static constexpr int NKV = 4;
static constexpr int NLAYER = 4;
static constexpr int VOCAB = 32000;
static constexpr int FF = 8192;
static constexpr int WINDOW = 1024;

// ---------------- block reduction helpers (256 threads = 4 waves) ----------------
__device__ __forceinline__ float blk_sum(float v) {
    __shared__ float sm[4];
    #pragma unroll
    for (int o = 32; o > 0; o >>= 1) v += __shfl_down(v, o, 64);
    int lane = threadIdx.x & 63, w = threadIdx.x >> 6;
    __syncthreads();
    if (lane == 0) sm[w] = v;
    __syncthreads();
    return sm[0] + sm[1] + sm[2] + sm[3];
}

__device__ __forceinline__ float blk_max(float v) {
    __shared__ float sm[4];
    #pragma unroll
    for (int o = 32; o > 0; o >>= 1) v = fmaxf(v, __shfl_down(v, o, 64));
    int lane = threadIdx.x & 63, w = threadIdx.x >> 6;
    __syncthreads();
    if (lane == 0) sm[w] = v;
    __syncthreads();
    return fmaxf(fmaxf(sm[0], sm[1]), fmaxf(sm[2], sm[3]));
}

// ---------------- elementwise kernels ----------------
__global__ void embed_kernel(const int* __restrict__ ids, const float* __restrict__ E,
                             float* __restrict__ h) {
    int d = blockIdx.x * 256 + threadIdx.x;
    int s = blockIdx.y;
    h[(long)s * D + d] = E[(long)ids[s] * D + d] * 45.25483399593904f; // sqrt(2048)
}

__global__ void rope_table_kernel(float* __restrict__ c, float* __restrict__ sn) {
    int i = threadIdx.x;   // 0..127
    int p = blockIdx.x;    // 0..S-1
    float inv = powf(10000.f, -(float)i / 128.f);
    float a = (float)p * inv;
    c[p * 128 + i] = cosf(a);
    sn[p * 128 + i] = sinf(a);
}

// fp32 -> bf16 conversion (grid-stride, 8 elems/thread/iter)
__global__ void cvt_bf16_kernel(const float* __restrict__ src, __hip_bfloat16* __restrict__ dst,
                                long n8) {
    long stride = (long)gridDim.x * 256;
    for (long i = (long)blockIdx.x * 256 + threadIdx.x; i < n8; i += stride) {
        long o = i * 8;
        float4 a = *(const float4*)(src + o);
        float4 b = *(const float4*)(src + o + 4);
        __hip_bfloat16 h8[8] = {
            __float2bfloat16(a.x), __float2bfloat16(a.y),
            __float2bfloat16(a.z), __float2bfloat16(a.w),
            __float2bfloat16(b.x), __float2bfloat16(b.y),
            __float2bfloat16(b.z), __float2bfloat16(b.w)};
        *(uint4*)(dst + o) = *(const uint4*)h8;
    }
}

// x = rms(h, w) -> bf16
__global__ void rms_bf16_kernel(const float* __restrict__ h, const float* __restrict__ w,
                                __hip_bfloat16* __restrict__ o) {
    int s = blockIdx.x;
    const float* row = h + (long)s * D;
    float vals[8], ss = 0.f;
    #pragma unroll
    for (int t = 0; t < 8; ++t) {
        int j = t * 256 + threadIdx.x;
        float v = row[j]; vals[t] = v; ss += v * v;
    }
    ss = blk_sum(ss);
    float r = rsqrtf(ss * (1.f / D) + 1e-6f);
    #pragma unroll
    for (int t = 0; t < 8; ++t) {
        int j = t * 256 + threadIdx.x;
        o[(long)s * D + j] = __float2bfloat16(vals[t] * r * (1.f + w[j]));
    }
}

// h += rms(t, w)
__global__ void resid_rms_kernel(float* __restrict__ h, const float* __restrict__ tt,
                                 const float* __restrict__ w) {
    int s = blockIdx.x;
    const float* row = tt + (long)s * D;
    float* hr = h + (long)s * D;
    float vals[8], ss = 0.f;
    #pragma unroll
    for (int t = 0; t < 8; ++t) {
        int j = t * 256 + threadIdx.x;
        float v = row[j]; vals[t] = v; ss += v * v;
    }
    ss = blk_sum(ss);
    float r = rsqrtf(ss * (1.f / D) + 1e-6f);
    #pragma unroll
    for (int t = 0; t < 8; ++t) {
        int j = t * 256 + threadIdx.x;
        hr[j] += vals[t] * r * (1.f + w[j]);
    }
}

// in-place RoPE on (S, H, 256) bf16; 128 threads per (s, head)
__global__ void rope_kernel(__hip_bfloat16* __restrict__ x, const float* __restrict__ cb,
                            const float* __restrict__ sb, int H) {
    int s = blockIdx.x, hh = blockIdx.y, i = threadIdx.x; // i in 0..127
    __hip_bfloat16* p = x + ((long)s * H + hh) * HD;
    float x1 = __bfloat162float(p[i]);
    float x2 = __bfloat162float(p[128 + i]);
    float c = cb[s * 128 + i], sn = sb[s * 128 + i];
    p[i]       = __float2bfloat16(x1 * c - x2 * sn);
    p[128 + i] = __float2bfloat16(x1 * sn + x2 * c);
}

// v (S, NKV*HD) bf16 -> vT (NKV, HD, S) bf16
__global__ void transpose_v_kernel(const __hip_bfloat16* __restrict__ v,
                                   __hip_bfloat16* __restrict__ vt) {
    __shared__ ushort tile[64][65];
    int s0 = blockIdx.x * 64, d0 = blockIdx.y * 64, kv = blockIdx.z;
    const ushort* vin = (const ushort*)v;
    ushort* vout = (ushort*)vt;
    #pragma unroll
    for (int it = 0; it < 4; ++it) {
        int slot = it * 256 + threadIdx.x;
        int r = slot >> 4, c4 = (slot & 15) << 2;
        ushort4 x = *(const ushort4*)(vin + (long)(s0 + r) * (NKV * HD) + kv * HD + d0 + c4);
        tile[r][c4] = x.x; tile[r][c4 + 1] = x.y; tile[r][c4 + 2] = x.z; tile[r][c4 + 3] = x.w;
    }
    __syncthreads();
    #pragma unroll
    for (int it = 0; it < 4; ++it) {
        int slot = it * 256 + threadIdx.x;
        int rr = slot >> 4, c4 = (slot & 15) << 2;
        ushort4 y;
        y.x = tile[c4][rr]; y.y = tile[c4 + 1][rr]; y.z = tile[c4 + 2][rr]; y.w = tile[c4 + 3][rr];
        *(ushort4*)(vout + (long)kv * HD * S + (long)(d0 + rr) * S + s0 + c4) = y;
    }
}

// scores (NH,S,S) f32 -> probs bf16, with scale, tanh softcap, mask, softmax
__global__ void softmax_kernel(const float* __restrict__ sc, __hip_bfloat16* __restrict__ pr,
                               int isLocal) {
    int i = blockIdx.x, hh = blockIdx.y;
    const float* row = sc + ((long)hh * S + i) * S;
    __hip_bfloat16* orow = pr + ((long)hh * S + i) * S;
    float vals[8];
    float m = -3.0e38f;
    #pragma unroll
    for (int t = 0; t < 8; ++t) {
        int j = t * 256 + threadIdx.x;
        bool valid = (j <= i) && (!isLocal || (i - j) < WINDOW);
        float v = tanhf(row[j] * (0.0625f / 50.f)) * 50.f; // SCALE=1/16, softcap 50
        vals[t] = valid ? v : -3.0e38f;
        m = fmaxf(m, vals[t]);
    }
    m = blk_max(m);
    float ps[8], ssum = 0.f;
    #pragma unroll
    for (int t = 0; t < 8; ++t) {
        float p = (vals[t] > -1.0e38f) ? __expf(vals[t] - m) : 0.f;
        ps[t] = p; ssum += p;
    }
    ssum = blk_sum(ssum);
    float inv = 1.f / ssum;
    #pragma unroll
    for (int t = 0; t < 8; ++t) {
        int j = t * 256 + threadIdx.x;
        orow[j] = __float2bfloat16(ps[t] * inv);
    }
}

// gate *= up
__global__ void mul_bf16_kernel(__hip_bfloat16* __restrict__ g,
                                const __hip_bfloat16* __restrict__ u) {
    long i = ((long)blockIdx.x * 256 + threadIdx.x) * 8;
    uint4 gv = *(const uint4*)(g + i);
    uint4 uv = *(const uint4*)(u + i);
    const __hip_bfloat16* gp = (const __hip_bfloat16*)&gv;
    const __hip_bfloat16* up = (const __hip_bfloat16*)&uv;
    __hip_bfloat16 o[8];
    #pragma unroll
    for (int j = 0; j < 8; ++j)
        o[j] = __float2bfloat16(__bfloat162float(gp[j]) * __bfloat162float(up[j]));
    *(uint4*)(g + i) = *(const uint4*)o;
}

// ---------------- fast GEMM: C[M,N] = A[M,K] * B[N,K]^T, both bf16 ----------------
// 128x128 tile, BK=32, global_load_lds width 16, XOR-swizzled LDS (chunk ^= (row>>1)&3),
// XCD-chunked 1-D grid remap. EPI: 0=f32, 1=bf16, 2=gelu->bf16, 3=tanh(x/30)*30->f32
template<int EPI>
__global__ __launch_bounds__(256) void gemm_bf16(
    const __hip_bfloat16* __restrict__ A, const __hip_bfloat16* __restrict__ B,
    void* __restrict__ Cv, int K, int lda, int ldb, int ldc,
    long aBatch, long bBatch, long cBatch, int bzDiv, int gx) {
    __shared__ __hip_bfloat16 As[128 * 32];
    __shared__ __hip_bfloat16 Bs[128 * 32];
    const int tid = threadIdx.x;
    const int nwg = gridDim.x;
    const int orig = blockIdx.x;
    const int wgid = (orig & 7) * (nwg >> 3) + (orig >> 3); // nwg % 8 == 0 at all call sites
    const int bx = wgid % gx, by = wgid / gx;
    const int bz = blockIdx.z;

    const __hip_bfloat16* Ab = A + (long)bz * aBatch + (long)bx * 128 * lda;
    const __hip_bfloat16* Bb = B + (long)(bz / bzDiv) * bBatch + (long)by * 128 * ldb;

    const int w = tid >> 6, l = tid & 63;
    // staging decode: linear LDS byte offset o = w*2048 + i*1024 + l*16
    // row = o>>6 (64B rows = 32 bf16), chunk = (o>>4)&3; source chunk = chunk ^ ((row>>1)&3)
    int srow[2], scsrc[2], sdst[2];
    #pragma unroll
    for (int i = 0; i < 2; ++i) {
        int o = w * 2048 + i * 1024 + l * 16;
        int row = o >> 6;
        int chunk = (o >> 4) & 3;
        srow[i]  = row;
        scsrc[i] = (chunk ^ ((row >> 1) & 3)) * 8;  // element offset within the 64B row
        sdst[i]  = w * 1024 + i * 512;              // wave-uniform base (elements)
    }

    const int wr = (w >> 1) * 64, wc = (w & 1) * 64;
    const int fr = l & 15;
    const int g  = l >> 4; // k-chunk index 0..3

    floatx4 acc[4][4] = {};

    for (int k0 = 0; k0 < K; k0 += 32) {
        __syncthreads();
        #pragma unroll
        for (int i = 0; i < 2; ++i) {
            __builtin_amdgcn_global_load_lds(
                (kGlb*)(Ab + (long)srow[i] * lda + k0 + scsrc[i]),
                (kLds*)(As + sdst[i]), 16, 0, 0);
            __builtin_amdgcn_global_load_lds(
                (kGlb*)(Bb + (long)srow[i] * ldb + k0 + scsrc[i]),
                (kLds*)(Bs + sdst[i]), 16, 0, 0);
        }
        __syncthreads();
        bf16x8 af[4], bfr[4];
        const char* AsB = (const char*)As;
        const char* BsB = (const char*)Bs;
        #pragma unroll
        for (int i = 0; i < 4; ++i) {
            int ra = wr + i * 16 + fr;
            af[i] = *(const bf16x8*)(AsB + ra * 64 + (((g ^ ((ra >> 1) & 3))) << 4));
        }
        #pragma unroll
        for (int j = 0; j < 4; ++j) {
            int rb = wc + j * 16 + fr;
            bfr[j] = *(const bf16x8*)(BsB + rb * 64 + (((g ^ ((rb >> 1) & 3))) << 4));
        }
        #pragma unroll
        for (int i = 0; i < 4; ++i) {
            #pragma unroll
            for (int j = 0; j < 4; ++j)
                acc[i][j] = __builtin_amdgcn_mfma_f32_16x16x32_bf16(af[i], bfr[j], acc[i][j], 0, 0, 0);
        }
    }

    const long cTile = (long)bz * cBatch + (long)bx * 128 * ldc + (long)by * 128;
    const int rg = (l >> 4) * 4;
    #pragma unroll
    for (int i = 0; i < 4; ++i) {
        #pragma unroll
        for (int j = 0; j < 4; ++j) {
            #pragma unroll
            for (int r = 0; r < 4; ++r) {
                int row = wr + i * 16 + rg + r;
                int col = wc + j * 16 + fr;
                long idx = cTile + (long)row * ldc + col;
                float v = acc[i][j][r];
                if constexpr (EPI == 0) {
                    ((float*)Cv)[idx] = v;
                } else if constexpr (EPI == 1) {
                    ((__hip_bfloat16*)Cv)[idx] = __float2bfloat16(v);
                } else if constexpr (EPI == 2) {
                    float gg = 0.5f * v * (1.f + tanhf(0.7978845608f * (v + 0.044715f * v * v * v)));
                    ((__hip_bfloat16*)Cv)[idx] = __float2bfloat16(gg);
                } else {
                    ((float*)Cv)[idx] = tanhf(v * (1.f / 30.f)) * 30.f;
                }
            }
        }
    }
}

// ---------------- fallback GEMM with fp32 B staging (used only if ws too small) ----------------
template<int EPI>
__global__ __launch_bounds__(256) void gemm_f32w(
    const __hip_bfloat16* __restrict__ A, const float* __restrict__ Bv,
    void* __restrict__ Cv, int K, int lda, int ldb, int ldc) {
    __shared__ __hip_bfloat16 As[128][32];
    __shared__ __hip_bfloat16 Bs[128][32];
    const int tid = threadIdx.x;
    const __hip_bfloat16* Ab = A + (long)blockIdx.x * 128 * lda;
    const float* Bb = Bv + (long)blockIdx.y * 128 * ldb;
    const int wid = tid >> 6, lane = tid & 63;
    const int wr = (wid >> 1) * 64, wc = (wid & 1) * 64;
    const int fr = lane & 15;
    const int kb = (lane >> 4) * 8;
    floatx4 acc[4][4] = {};
    for (int k0 = 0; k0 < K; k0 += 32) {
        __syncthreads();
        #pragma unroll
        for (int it = 0; it < 2; ++it) {
            int slot = tid + it * 256;
            int r = slot >> 2, c8 = (slot & 3) * 8;
            *reinterpret_cast<uint4*>(&As[r][c8]) =
                *reinterpret_cast<const uint4*>(Ab + (long)r * lda + k0 + c8);
        }
        #pragma unroll
        for (int it = 0; it < 4; ++it) {
            int slot = tid + it * 256;
            int r = slot >> 3, c4 = (slot & 7) * 4;
            float4 f = *reinterpret_cast<const float4*>(Bb + (long)r * ldb + k0 + c4);
            __hip_bfloat16 t4[4] = {__float2bfloat16(f.x), __float2bfloat16(f.y),
                                    __float2bfloat16(f.z), __float2bfloat16(f.w)};
            *reinterpret_cast<ushort4*>(&Bs[r][c4]) = *reinterpret_cast<const ushort4*>(t4);
        }
        __syncthreads();
        bf16x8 af[4], bfr[4];
        #pragma unroll
        for (int i = 0; i < 4; ++i)
            af[i] = *reinterpret_cast<const bf16x8*>(&As[wr + i * 16 + fr][kb]);
        #pragma unroll
        for (int j = 0; j < 4; ++j)
            bfr[j] = *reinterpret_cast<const bf16x8*>(&Bs[wc + j * 16 + fr][kb]);
        #pragma unroll
        for (int i = 0; i < 4; ++i)
            #pragma unroll
            for (int j = 0; j < 4; ++j)
                acc[i][j] = __builtin_amdgcn_mfma_f32_16x16x32_bf16(af[i], bfr[j], acc[i][j], 0, 0, 0);
    }
    const long cTile = (long)blockIdx.x * 128 * ldc + (long)blockIdx.y * 128;
    const int rg = (lane >> 4) * 4;
    #pragma unroll
    for (int i = 0; i < 4; ++i)
        #pragma unroll
        for (int j = 0; j < 4; ++j)
            #pragma unroll
            for (int r = 0; r < 4; ++r) {
                int row = wr + i * 16 + rg + r;
                int col = wc + j * 16 + fr;
                long idx = cTile + (long)row * ldc + col;
                float v = acc[i][j][r];
                if constexpr (EPI == 0) ((float*)Cv)[idx] = v;
                else if constexpr (EPI == 1) ((__hip_bfloat16*)Cv)[idx] = __float2bfloat16(v);
                else if constexpr (EPI == 2) {
                    float gg = 0.5f * v * (1.f + tanhf(0.7978845608f * (v + 0.044715f * v * v * v)));
                    ((__hip_bfloat16*)Cv)[idx] = __float2bfloat16(gg);
                } else ((float*)Cv)[idx] = tanhf(v * (1.f / 30.f)) * 30.f;
            }
}

// ---------------- host ----------------
extern "C" void kernel_launch(void* const* d_in, const int* in_sizes, int n_in,
                              void* d_out, int out_size, void* d_ws, size_t ws_size,
                              hipStream_t stream) {
    const int*   ids    = (const int*)d_in[0];
    const float* embedW = (const float*)d_in[1];
    const float* wq     = (const float*)d_in[2];
    const float* wk     = (const float*)d_in[3];
    const float* wv     = (const float*)d_in[4];
    const float* wo     = (const float*)d_in[5];
    const float* wg     = (const float*)d_in[6];
    const float* wu     = (const float*)d_in[7];
    const float* wd     = (const float*)d_in[8];
    const float* ln_in  = (const float*)d_in[9];
    const float* ln_pa  = (const float*)d_in[10];
    const float* ln_pf  = (const float*)d_in[11];
    const float* ln_pff = (const float*)d_in[12];
    const float* ln_f   = (const float*)d_in[13];
    const float* w_lm   = (const float*)d_in[14];
    float* out = (float*)d_out;

    char* ws = (char*)d_ws;
    size_t off = 0;
    auto alloc = [&](size_t bytes) -> void* {
        size_t o = (off + 255) & ~(size_t)255;
        off = o + bytes;
        return (void*)(ws + o);
    };

    float* h            = (float*)alloc((size_t)S * D * 4);
    __hip_bfloat16* xb  = (__hip_bfloat16*)alloc((size_t)S * D * 2);
    __hip_bfloat16* qb  = (__hip_bfloat16*)alloc((size_t)S * NH * HD * 2);
    __hip_bfloat16* kb  = (__hip_bfloat16*)alloc((size_t)S * NKV * HD * 2);
    __hip_bfloat16* vb  = (__hip_bfloat16*)alloc((size_t)S * NKV * HD * 2);
    __hip_bfloat16* vT  = (__hip_bfloat16*)alloc((size_t)NKV * HD * S * 2);
    __hip_bfloat16* ab  = (__hip_bfloat16*)alloc((size_t)S * NH * HD * 2);
    float* tmpf         = (float*)alloc((size_t)S * D * 4);
    __hip_bfloat16* gateb = (__hip_bfloat16*)alloc((size_t)S * FF * 2);
    __hip_bfloat16* upb   = (__hip_bfloat16*)alloc((size_t)S * FF * 2);
    float* cosb         = (float*)alloc((size_t)S * 128 * 4);
    float* sinb         = (float*)alloc((size_t)S * 128 * 4);
    float* scores       = (float*)alloc((size_t)NH * S * S * 4);
    __hip_bfloat16* probs = (__hip_bfloat16*)alloc((size_t)NH * S * S * 2);

    // bf16 weight copies
    const long nWq = 4L * 2048 * 2048, nWkv = 4L * 1024 * 2048, nWff = 4L * 8192 * 2048;
    const long nWlm = (long)VOCAB * D;
    __hip_bfloat16* wqb = (__hip_bfloat16*)alloc(nWq * 2);
    __hip_bfloat16* wkb = (__hip_bfloat16*)alloc(nWkv * 2);
    __hip_bfloat16* wvb = (__hip_bfloat16*)alloc(nWkv * 2);
    __hip_bfloat16* wob = (__hip_bfloat16*)alloc(nWq * 2);
    __hip_bfloat16* wgb = (__hip_bfloat16*)alloc(nWff * 2);
    __hip_bfloat16* wub = (__hip_bfloat16*)alloc(nWff * 2);
    __hip_bfloat16* wdb = (__hip_bfloat16*)alloc(nWff * 2);
    __hip_bfloat16* wlmb = (__hip_bfloat16*)alloc(nWlm * 2);
    const bool big = (off <= ws_size);
    (void)in_sizes; (void)n_in; (void)out_size;

    rope_table_kernel<<<dim3(S), dim3(128), 0, stream>>>(cosb, sinb);
    embed_kernel<<<dim3(D / 256, S), dim3(256), 0, stream>>>(ids, embedW, h);

    if (big) {
        auto cvt = [&](const float* s, __hip_bfloat16* dp, long n) {
            long n8 = n / 8;
            long want = (n8 + 255) / 256;
            int blocks = (int)(want < 2048 ? want : 2048);
            cvt_bf16_kernel<<<dim3(blocks), dim3(256), 0, stream>>>(s, dp, n8);
        };
        cvt(wq, wqb, nWq); cvt(wk, wkb, nWkv); cvt(wv, wvb, nWkv); cvt(wo, wob, nWq);
        cvt(wg, wgb, nWff); cvt(wu, wub, nWff); cvt(wd, wdb, nWff); cvt(w_lm, wlmb, nWlm);
    }

    const size_t SLq = (size_t)D * (NH * HD);
    const size_t SLkv = (size_t)D * (NKV * HD);
    const size_t SLff = (size_t)FF * D;

    // helper: launch fast bf16 GEMM with 1-D grid (gx*gy, 1, z)
    auto gemmW = [&](int epi, const __hip_bfloat16* A, const __hip_bfloat16* B, void* C,
                     int K, int lda, int ldb, int ldc, int gx, int gy) {
        dim3 grid(gx * gy, 1, 1);
        switch (epi) {
        case 0: gemm_bf16<0><<<grid, 256, 0, stream>>>(A, B, C, K, lda, ldb, ldc, 0, 0, 0, 1, gx); break;
        case 1: gemm_bf16<1><<<grid, 256, 0, stream>>>(A, B, C, K, lda, ldb, ldc, 0, 0, 0, 1, gx); break;
        case 2: gemm_bf16<2><<<grid, 256, 0, stream>>>(A, B, C, K, lda, ldb, ldc, 0, 0, 0, 1, gx); break;
        default: gemm_bf16<3><<<grid, 256, 0, stream>>>(A, B, C, K, lda, ldb, ldc, 0, 0, 0, 1, gx); break;
        }
    };

    for (int l = 0; l < NLAYER; ++l) {
        int isLocal = (l % 2 == 0) ? 1 : 0;
        rms_bf16_kernel<<<dim3(S), dim3(256), 0, stream>>>(h, ln_in + l * D, xb);
        if (big) {
            gemmW(1, xb, wqb + l * SLq, qb, D, D, D, NH * HD, 16, 16);
            gemmW(1, xb, wkb + l * SLkv, kb, D, D, D, NKV * HD, 16, 8);
            gemmW(1, xb, wvb + l * SLkv, vb, D, D, D, NKV * HD, 16, 8);
        } else {
            gemm_f32w<1><<<dim3(16, 16), 256, 0, stream>>>(xb, wq + l * SLq, qb, D, D, D, NH * HD);
            gemm_f32w<1><<<dim3(16, 8), 256, 0, stream>>>(xb, wk + l * SLkv, kb, D, D, D, NKV * HD);
            gemm_f32w<1><<<dim3(16, 8), 256, 0, stream>>>(xb, wv + l * SLkv, vb, D, D, D, NKV * HD);
        }
        rope_kernel<<<dim3(S, NH), dim3(128), 0, stream>>>(qb, cosb, sinb, NH);
        rope_kernel<<<dim3(S, NKV), dim3(128), 0, stream>>>(kb, cosb, sinb, NKV);
        transpose_v_kernel<<<dim3(S / 64, HD / 64, NKV), 256, 0, stream>>>(vb, vT);
        // scores = q @ k^T per head (batched over z = head)
        gemm_bf16<0><<<dim3(256, 1, NH), 256, 0, stream>>>(
            qb, kb, scores, HD, NH * HD, NKV * HD, S, (long)HD, (long)HD, (long)S * S, 2, 16);
        softmax_kernel<<<dim3(S, NH), dim3(256), 0, stream>>>(scores, probs, isLocal);
        // a = probs @ vT
        gemm_bf16<1><<<dim3(32, 1, NH), 256, 0, stream>>>(
            probs, vT, ab, S, S, S, NH * HD, (long)S * S, (long)HD * S, (long)HD, 2, 16);
        if (big) {
            gemmW(0, ab, wob + l * SLq, tmpf, NH * HD, NH * HD, NH * HD, D, 16, 16);
        } else {
            gemm_f32w<0><<<dim3(16, 16), 256, 0, stream>>>(ab, wo + l * SLq, tmpf, NH * HD, NH * HD, NH * HD, D);
        }
        resid_rms_kernel<<<dim3(S), dim3(256), 0, stream>>>(h, tmpf, ln_pa + l * D);
        rms_bf16_kernel<<<dim3(S), dim3(256), 0, stream>>>(h, ln_pf + l * D, xb);
        if (big) {
            gemmW(2, xb, wgb + l * SLff, gateb, D, D, D, FF, 16, 64);
            gemmW(1, xb, wub + l * SLff, upb, D, D, D, FF, 16, 64);
        } else {
            gemm_f32w<2><<<dim3(16, 64), 256, 0, stream>>>(xb, wg + l * SLff, gateb, D, D, D, FF);
            gemm_f32w<1><<<dim3(16, 64), 256, 0, stream>>>(xb, wu + l * SLff, upb, D, D, D, FF);
        }
        mul_bf16_kernel<<<dim3((S * FF) / (256 * 8)), 256, 0, stream>>>(gateb, upb);
        if (big) {
            gemmW(0, gateb, wdb + l * SLff, tmpf, FF, FF, FF, D, 16, 16);
        } else {
            gemm_f32w<0><<<dim3(16, 16), 256, 0, stream>>>(gateb, wd + l * SLff, tmpf, FF, FF, FF, D);
        }
        resid_rms_kernel<<<dim3(S), dim3(256), 0, stream>>>(h, tmpf, ln_pff + l * D);
    }

    rms_bf16_kernel<<<dim3(S), dim3(256), 0, stream>>>(h, ln_f, xb);
    if (big) {
        gemmW(3, xb, wlmb, out, D, D, D, VOCAB, 16, VOCAB / 128);
    } else {
        gemm_f32w<3><<<dim3(16, VOCAB / 128), 256, 0, stream>>>(xb, w_lm, out, D, D, D, VOCAB);
    }
}

// Round 3
// 3367.473 us; speedup vs baseline: 1.5405x; 1.3150x over previous
//
#include <hip/hip_runtime.h>
#include <hip/hip_bf16.h>

typedef __attribute__((ext_vector_type(8))) __bf16 bf16x8;
typedef __attribute__((ext_vector_type(4))) float floatx4;

typedef __attribute__((address_space(1))) const unsigned char kGlb;
typedef __attribute__((address_space(3))) unsigned char kLds;

static constexpr int S = 2048;
static constexpr int D = 2048;
static constexpr int HD = 256;
static constexpr int NH = 8;
static constexpr int NKV = 4;
static constexpr int NLAYER = 4;
static constexpr int VOCAB = 32000;
static constexpr int FF = 8192;
static constexpr int WINDOW = 1024;

// ---------------- block reduction helpers (256 threads = 4 waves) ----------------
__device__ __forceinline__ float blk_sum(float v) {
    __shared__ float sm[4];
    #pragma unroll
    for (int o = 32; o > 0; o >>= 1) v += __shfl_down(v, o, 64);
    int lane = threadIdx.x & 63, w = threadIdx.x >> 6;
    __syncthreads();
    if (lane == 0) sm[w] = v;
    __syncthreads();
    return sm[0] + sm[1] + sm[2] + sm[3];
}

__device__ __forceinline__ float blk_max(float v) {
    __shared__ float sm[4];
    #pragma unroll
    for (int o = 32; o > 0; o >>= 1) v = fmaxf(v, __shfl_down(v, o, 64));
    int lane = threadIdx.x & 63, w = threadIdx.x >> 6;
    __syncthreads();
    if (lane == 0) sm[w] = v;
    __syncthreads();
    return fmaxf(fmaxf(sm[0], sm[1]), fmaxf(sm[2], sm[3]));
}

// ---------------- elementwise kernels ----------------
__global__ void embed_kernel(const int* __restrict__ ids, const float* __restrict__ E,
                             float* __restrict__ h) {
    int d = blockIdx.x * 256 + threadIdx.x;
    int s = blockIdx.y;
    h[(long)s * D + d] = E[(long)ids[s] * D + d] * 45.25483399593904f; // sqrt(2048)
}

__global__ void rope_table_kernel(float* __restrict__ c, float* __restrict__ sn) {
    int i = threadIdx.x;   // 0..127
    int p = blockIdx.x;    // 0..S-1
    float inv = powf(10000.f, -(float)i / 128.f);
    float a = (float)p * inv;
    c[p * 128 + i] = cosf(a);
    sn[p * 128 + i] = sinf(a);
}

// fp32 -> bf16 conversion (grid-stride, 8 elems/thread/iter)
__global__ void cvt_bf16_kernel(const float* __restrict__ src, __hip_bfloat16* __restrict__ dst,
                                long n8) {
    long stride = (long)gridDim.x * 256;
    for (long i = (long)blockIdx.x * 256 + threadIdx.x; i < n8; i += stride) {
        long o = i * 8;
        float4 a = *(const float4*)(src + o);
        float4 b = *(const float4*)(src + o + 4);
        __hip_bfloat16 h8[8] = {
            __float2bfloat16(a.x), __float2bfloat16(a.y),
            __float2bfloat16(a.z), __float2bfloat16(a.w),
            __float2bfloat16(b.x), __float2bfloat16(b.y),
            __float2bfloat16(b.z), __float2bfloat16(b.w)};
        *(uint4*)(dst + o) = *(const uint4*)h8;
    }
}

// x = rms(h, w) -> bf16
__global__ void rms_bf16_kernel(const float* __restrict__ h, const float* __restrict__ w,
                                __hip_bfloat16* __restrict__ o) {
    int s = blockIdx.x;
    const float* row = h + (long)s * D;
    float vals[8], ss = 0.f;
    #pragma unroll
    for (int t = 0; t < 8; ++t) {
        int j = t * 256 + threadIdx.x;
        float v = row[j]; vals[t] = v; ss += v * v;
    }
    ss = blk_sum(ss);
    float r = rsqrtf(ss * (1.f / D) + 1e-6f);
    #pragma unroll
    for (int t = 0; t < 8; ++t) {
        int j = t * 256 + threadIdx.x;
        o[(long)s * D + j] = __float2bfloat16(vals[t] * r * (1.f + w[j]));
    }
}

// h += rms(t, w)
__global__ void resid_rms_kernel(float* __restrict__ h, const float* __restrict__ tt,
                                 const float* __restrict__ w) {
    int s = blockIdx.x;
    const float* row = tt + (long)s * D;
    float* hr = h + (long)s * D;
    float vals[8], ss = 0.f;
    #pragma unroll
    for (int t = 0; t < 8; ++t) {
        int j = t * 256 + threadIdx.x;
        float v = row[j]; vals[t] = v; ss += v * v;
    }
    ss = blk_sum(ss);
    float r = rsqrtf(ss * (1.f / D) + 1e-6f);
    #pragma unroll
    for (int t = 0; t < 8; ++t) {
        int j = t * 256 + threadIdx.x;
        hr[j] += vals[t] * r * (1.f + w[j]);
    }
}

// in-place RoPE on rows with stride ldx; head offset hh*HD; 128 threads per (s, head)
__global__ void rope_kernel(__hip_bfloat16* __restrict__ x, const float* __restrict__ cb,
                            const float* __restrict__ sb, int ldx) {
    int s = blockIdx.x, hh = blockIdx.y, i = threadIdx.x; // i in 0..127
    __hip_bfloat16* p = x + (long)s * ldx + hh * HD;
    float x1 = __bfloat162float(p[i]);
    float x2 = __bfloat162float(p[128 + i]);
    float c = cb[s * 128 + i], sn = sb[s * 128 + i];
    p[i]       = __float2bfloat16(x1 * c - x2 * sn);
    p[128 + i] = __float2bfloat16(x1 * sn + x2 * c);
}

// v rows (stride ldv, base already offset to v region) -> vT (NKV, HD, S) bf16
__global__ void transpose_v_kernel(const __hip_bfloat16* __restrict__ v,
                                   __hip_bfloat16* __restrict__ vt, int ldv) {
    __shared__ ushort tile[64][65];
    int s0 = blockIdx.x * 64, d0 = blockIdx.y * 64, kv = blockIdx.z;
    const ushort* vin = (const ushort*)v;
    ushort* vout = (ushort*)vt;
    #pragma unroll
    for (int it = 0; it < 4; ++it) {
        int slot = it * 256 + threadIdx.x;
        int r = slot >> 4, c4 = (slot & 15) << 2;
        ushort4 x = *(const ushort4*)(vin + (long)(s0 + r) * ldv + kv * HD + d0 + c4);
        tile[r][c4] = x.x; tile[r][c4 + 1] = x.y; tile[r][c4 + 2] = x.z; tile[r][c4 + 3] = x.w;
    }
    __syncthreads();
    #pragma unroll
    for (int it = 0; it < 4; ++it) {
        int slot = it * 256 + threadIdx.x;
        int rr = slot >> 4, c4 = (slot & 15) << 2;
        ushort4 y;
        y.x = tile[c4][rr]; y.y = tile[c4 + 1][rr]; y.z = tile[c4 + 2][rr]; y.w = tile[c4 + 3][rr];
        *(ushort4*)(vout + (long)kv * HD * S + (long)(d0 + rr) * S + s0 + c4) = y;
    }
}

// scores (NH,S,S) f32 -> probs bf16, with scale, tanh softcap, mask, softmax.
// Skips loads of fully-invalid 256-chunks (stale data there is finite and discarded).
__global__ void softmax_kernel(const float* __restrict__ sc, __hip_bfloat16* __restrict__ pr,
                               int isLocal) {
    int i = blockIdx.x, hh = blockIdx.y;
    const float* row = sc + ((long)hh * S + i) * S;
    __hip_bfloat16* orow = pr + ((long)hh * S + i) * S;
    int lo = isLocal ? max(0, i - (WINDOW - 1)) : 0;
    float vals[8];
    float m = -3.0e38f;
    #pragma unroll
    for (int t = 0; t < 8; ++t) {
        int j = t * 256 + threadIdx.x;
        bool chunkAny = (t * 256 <= i) && (t * 256 + 255 >= lo);
        if (chunkAny) {
            bool valid = (j <= i) && (j >= lo);
            float v = tanhf(row[j] * (0.0625f / 50.f)) * 50.f; // SCALE=1/16, softcap 50
            vals[t] = valid ? v : -3.0e38f;
            m = fmaxf(m, vals[t]);
        } else {
            vals[t] = -3.0e38f;
        }
    }
    m = blk_max(m);
    float ps[8], ssum = 0.f;
    #pragma unroll
    for (int t = 0; t < 8; ++t) {
        float p = (vals[t] > -1.0e38f) ? __expf(vals[t] - m) : 0.f;
        ps[t] = p; ssum += p;
    }
    ssum = blk_sum(ssum);
    float inv = 1.f / ssum;
    #pragma unroll
    for (int t = 0; t < 8; ++t) {
        int j = t * 256 + threadIdx.x;
        orow[j] = __float2bfloat16(ps[t] * inv);
    }
}

// gate half *= up half, packed gu[S][16384] (gate cols 0..8191, up 8192..16383)
__global__ void mul_gu_kernel(__hip_bfloat16* __restrict__ gu) {
    long idx = ((long)blockIdx.x * 256 + threadIdx.x) * 8; // gate-element index
    long s = idx >> 13;          // / 8192
    long f = idx & 8191;
    __hip_bfloat16* gp = gu + s * 16384 + f;
    const __hip_bfloat16* up = gu + s * 16384 + 8192 + f;
    uint4 gv = *(const uint4*)gp;
    uint4 uv = *(const uint4*)up;
    const __hip_bfloat16* gb = (const __hip_bfloat16*)&gv;
    const __hip_bfloat16* ub = (const __hip_bfloat16*)&uv;
    __hip_bfloat16 o[8];
    #pragma unroll
    for (int j = 0; j < 8; ++j)
        o[j] = __float2bfloat16(__bfloat162float(gb[j]) * __bfloat162float(ub[j]));
    *(uint4*)gp = *(const uint4*)o;
}

// ---------------- 128x128 GEMM (attention): C[M,N] = A[M,K] * B[N,K]^T, both bf16 ----------------
// kMode: 0 none; 1 causal score-tile skip; 2 local score-tile skip;
//        3 causal PV K-range; 4 local PV K-range
template<int EPI>
__global__ __launch_bounds__(256) void gemm_bf16(
    const __hip_bfloat16* __restrict__ A, const __hip_bfloat16* __restrict__ B,
    void* __restrict__ Cv, int K, int lda, int ldb, int ldc,
    long aBatch, long bBatch, long cBatch, int bzDiv, int gx, int kMode) {
    __shared__ __hip_bfloat16 As[128 * 32];
    __shared__ __hip_bfloat16 Bs[128 * 32];
    const int tid = threadIdx.x;
    const int nwg = gridDim.x;
    const int orig = blockIdx.x;
    const int wgid = (orig & 7) * (nwg >> 3) + (orig >> 3); // nwg % 8 == 0 at all call sites
    const int bx = wgid % gx, by = wgid / gx;
    const int bz = blockIdx.z;

    int kstart = 0, kend = K;
    if (kMode == 1) { if (by > bx) return; }
    else if (kMode == 2) { if (by > bx || bx - by >= 9) return; }
    else if (kMode == 3) { kend = min(K, (bx + 1) * 128); }
    else if (kMode == 4) { kend = min(K, (bx + 1) * 128); kstart = max(0, (bx - 8) * 128); }

    const __hip_bfloat16* Ab = A + (long)bz * aBatch + (long)bx * 128 * lda;
    const __hip_bfloat16* Bb = B + (long)(bz / bzDiv) * bBatch + (long)by * 128 * ldb;

    const int w = tid >> 6, l = tid & 63;
    int srow[2], scsrc[2], sdst[2];
    #pragma unroll
    for (int i = 0; i < 2; ++i) {
        int o = w * 2048 + i * 1024 + l * 16;
        int row = o >> 6;
        int chunk = (o >> 4) & 3;
        srow[i]  = row;
        scsrc[i] = (chunk ^ ((row >> 1) & 3)) * 8;
        sdst[i]  = w * 1024 + i * 512;
    }

    const int wr = (w >> 1) * 64, wc = (w & 1) * 64;
    const int fr = l & 15;
    const int g  = l >> 4;

    floatx4 acc[4][4] = {};

    for (int k0 = kstart; k0 < kend; k0 += 32) {
        __syncthreads();
        #pragma unroll
        for (int i = 0; i < 2; ++i) {
            __builtin_amdgcn_global_load_lds(
                (kGlb*)(Ab + (long)srow[i] * lda + k0 + scsrc[i]),
                (kLds*)(As + sdst[i]), 16, 0, 0);
            __builtin_amdgcn_global_load_lds(
                (kGlb*)(Bb + (long)srow[i] * ldb + k0 + scsrc[i]),
                (kLds*)(Bs + sdst[i]), 16, 0, 0);
        }
        __syncthreads();
        bf16x8 af[4], bfr[4];
        const char* AsB = (const char*)As;
        const char* BsB = (const char*)Bs;
        #pragma unroll
        for (int i = 0; i < 4; ++i) {
            int ra = wr + i * 16 + fr;
            af[i] = *(const bf16x8*)(AsB + ra * 64 + (((g ^ ((ra >> 1) & 3))) << 4));
        }
        #pragma unroll
        for (int j = 0; j < 4; ++j) {
            int rb = wc + j * 16 + fr;
            bfr[j] = *(const bf16x8*)(BsB + rb * 64 + (((g ^ ((rb >> 1) & 3))) << 4));
        }
        #pragma unroll
        for (int i = 0; i < 4; ++i) {
            #pragma unroll
            for (int j = 0; j < 4; ++j)
                acc[i][j] = __builtin_amdgcn_mfma_f32_16x16x32_bf16(af[i], bfr[j], acc[i][j], 0, 0, 0);
        }
    }

    const long cTile = (long)bz * cBatch + (long)bx * 128 * ldc + (long)by * 128;
    const int rg = (l >> 4) * 4;
    #pragma unroll
    for (int i = 0; i < 4; ++i) {
        #pragma unroll
        for (int j = 0; j < 4; ++j) {
            #pragma unroll
            for (int r = 0; r < 4; ++r) {
                int row = wr + i * 16 + rg + r;
                int col = wc + j * 16 + fr;
                long idx = cTile + (long)row * ldc + col;
                float v = acc[i][j][r];
                if constexpr (EPI == 0) {
                    ((float*)Cv)[idx] = v;
                } else {
                    ((__hip_bfloat16*)Cv)[idx] = __float2bfloat16(v);
                }
            }
        }
    }
}

// ---------------- 256x256 pipelined GEMM (weights): counted-vmcnt, raw barriers ----------------
// BK=32, 8 waves (2Mx4N), 4 LDS buffers (128 KiB), depth-3 prefetch, vmcnt(8) steady state.
// EPI: 0=f32, 1=bf16, 3=tanh(x/30)*30->f32, 4=gelu if global col<8192 else plain ->bf16
template<int EPI>
__global__ __launch_bounds__(512, 2) void gemm_pipe(
    const __hip_bfloat16* __restrict__ A, const __hip_bfloat16* __restrict__ B,
    void* __restrict__ Cv, int K, int lda, int ldb, int ldc, int gx) {
    __shared__ __hip_bfloat16 lds[4][2][8192]; // [buf][A/B][256*32], 128 KiB
    const int tid = threadIdx.x;
    const int nwg = gridDim.x;
    const int orig = blockIdx.x;
    const int wgid = (orig & 7) * (nwg >> 3) + (orig >> 3); // nwg % 8 == 0 at all call sites
    const int bx = wgid % gx, by = wgid / gx;

    const __hip_bfloat16* Ab = A + (long)bx * 256 * lda;
    const __hip_bfloat16* Bb = B + (long)by * 256 * ldb;

    const int w = tid >> 6, l = tid & 63;
    const int wm = w >> 2, wn = w & 3;
    const int wrow = wm * 128, wcol = wn * 64;
    const int fr = l & 15, g = l >> 4;
    const int srow0 = tid >> 2;   // staging row (+ i*128)
    const int schunk = tid & 3;   // staging 16B chunk within 64B row

    floatx4 acc[8][4] = {};

    auto stage = [&](int t, int buf) {
        const int k0 = t * 32;
        #pragma unroll
        for (int i = 0; i < 2; ++i) {
            int row = srow0 + i * 128;
            int scol = ((schunk ^ ((row >> 1) & 3)) << 3); // pre-swizzled source column (elems)
            __builtin_amdgcn_global_load_lds(
                (kGlb*)(Ab + (long)row * lda + k0 + scol),
                (kLds*)(&lds[buf][0][0] + tid * 8 + i * 4096), 16, 0, 0);
            __builtin_amdgcn_global_load_lds(
                (kGlb*)(Bb + (long)row * ldb + k0 + scol),
                (kLds*)(&lds[buf][1][0] + tid * 8 + i * 4096), 16, 0, 0);
        }
    };

    auto compute = [&](int buf) {
        const char* AsB = (const char*)&lds[buf][0][0];
        const char* BsB = (const char*)&lds[buf][1][0];
        bf16x8 af[8], bfv[4];
        #pragma unroll
        for (int mi = 0; mi < 8; ++mi) {
            int ra = wrow + mi * 16 + fr;
            af[mi] = *(const bf16x8*)(AsB + ra * 64 + ((g ^ ((ra >> 1) & 3)) << 4));
        }
        #pragma unroll
        for (int ni = 0; ni < 4; ++ni) {
            int rb = wcol + ni * 16 + fr;
            bfv[ni] = *(const bf16x8*)(BsB + rb * 64 + ((g ^ ((rb >> 1) & 3)) << 4));
        }
        __builtin_amdgcn_s_setprio(1);
        #pragma unroll
        for (int mi = 0; mi < 8; ++mi) {
            #pragma unroll
            for (int ni = 0; ni < 4; ++ni)
                acc[mi][ni] = __builtin_amdgcn_mfma_f32_16x16x32_bf16(af[mi], bfv[ni], acc[mi][ni], 0, 0, 0);
        }
        __builtin_amdgcn_s_setprio(0);
    };

    #define PIPE_FENCE(N)                                        \
        asm volatile("s_waitcnt vmcnt(" #N ")" ::: "memory");    \
        __builtin_amdgcn_sched_barrier(0);                       \
        __builtin_amdgcn_s_barrier();                            \
        __builtin_amdgcn_sched_barrier(0);

    const int nt = K >> 5; // K multiple of 32, nt >= 4 at all call sites
    stage(0, 0); stage(1, 1); stage(2, 2);
    PIPE_FENCE(8)
    for (int t = 0; t < nt - 3; ++t) {
        stage(t + 3, (t + 3) & 3);
        compute(t & 3);
        PIPE_FENCE(8)
    }
    compute((nt - 3) & 3);
    PIPE_FENCE(4)
    compute((nt - 2) & 3);
    PIPE_FENCE(0)
    compute((nt - 1) & 3);
    #undef PIPE_FENCE

    const long cBase = (long)bx * 256 * ldc + (long)by * 256;
    const int rg = (l >> 4) * 4;
    #pragma unroll
    for (int mi = 0; mi < 8; ++mi) {
        #pragma unroll
        for (int ni = 0; ni < 4; ++ni) {
            #pragma unroll
            for (int r = 0; r < 4; ++r) {
                int row = wrow + mi * 16 + rg + r;
                int col = wcol + ni * 16 + fr;
                long idx = cBase + (long)row * ldc + col;
                float v = acc[mi][ni][r];
                if constexpr (EPI == 0) {
                    ((float*)Cv)[idx] = v;
                } else if constexpr (EPI == 1) {
                    ((__hip_bfloat16*)Cv)[idx] = __float2bfloat16(v);
                } else if constexpr (EPI == 3) {
                    ((float*)Cv)[idx] = tanhf(v * (1.f / 30.f)) * 30.f;
                } else { // EPI 4: fused gate|up epilogue
                    int colg = by * 256 + col;
                    float o = v;
                    if (colg < 8192)
                        o = 0.5f * v * (1.f + tanhf(0.7978845608f * (v + 0.044715f * v * v * v)));
                    ((__hip_bfloat16*)Cv)[idx] = __float2bfloat16(o);
                }
            }
        }
    }
}

// ---------------- fallback GEMM with fp32 B staging (used only if ws too small) ----------------
template<int EPI>
__global__ __launch_bounds__(256) void gemm_f32w(
    const __hip_bfloat16* __restrict__ A, const float* __restrict__ Bv,
    void* __restrict__ Cv, int K, int lda, int ldb, int ldc) {
    __shared__ __hip_bfloat16 As[128][32];
    __shared__ __hip_bfloat16 Bs[128][32];
    const int tid = threadIdx.x;
    const __hip_bfloat16* Ab = A + (long)blockIdx.x * 128 * lda;
    const float* Bb = Bv + (long)blockIdx.y * 128 * ldb;
    const int wid = tid >> 6, lane = tid & 63;
    const int wr = (wid >> 1) * 64, wc = (wid & 1) * 64;
    const int fr = lane & 15;
    const int kb = (lane >> 4) * 8;
    floatx4 acc[4][4] = {};
    for (int k0 = 0; k0 < K; k0 += 32) {
        __syncthreads();
        #pragma unroll
        for (int it = 0; it < 2; ++it) {
            int slot = tid + it * 256;
            int r = slot >> 2, c8 = (slot & 3) * 8;
            *reinterpret_cast<uint4*>(&As[r][c8]) =
                *reinterpret_cast<const uint4*>(Ab + (long)r * lda + k0 + c8);
        }
        #pragma unroll
        for (int it = 0; it < 4; ++it) {
            int slot = tid + it * 256;
            int r = slot >> 3, c4 = (slot & 7) * 4;
            float4 f = *reinterpret_cast<const float4*>(Bb + (long)r * ldb + k0 + c4);
            __hip_bfloat16 t4[4] = {__float2bfloat16(f.x), __float2bfloat16(f.y),
                                    __float2bfloat16(f.z), __float2bfloat16(f.w)};
            *reinterpret_cast<ushort4*>(&Bs[r][c4]) = *reinterpret_cast<const ushort4*>(t4);
        }
        __syncthreads();
        bf16x8 af[4], bfr[4];
        #pragma unroll
        for (int i = 0; i < 4; ++i)
            af[i] = *reinterpret_cast<const bf16x8*>(&As[wr + i * 16 + fr][kb]);
        #pragma unroll
        for (int j = 0; j < 4; ++j)
            bfr[j] = *reinterpret_cast<const bf16x8*>(&Bs[wc + j * 16 + fr][kb]);
        #pragma unroll
        for (int i = 0; i < 4; ++i)
            #pragma unroll
            for (int j = 0; j < 4; ++j)
                acc[i][j] = __builtin_amdgcn_mfma_f32_16x16x32_bf16(af[i], bfr[j], acc[i][j], 0, 0, 0);
    }
    const long cTile = (long)blockIdx.x * 128 * ldc + (long)blockIdx.y * 128;
    const int rg = (lane >> 4) * 4;
    #pragma unroll
    for (int i = 0; i < 4; ++i)
        #pragma unroll
        for (int j = 0; j < 4; ++j)
            #pragma unroll
            for (int r = 0; r < 4; ++r) {
                int row = wr + i * 16 + rg + r;
                int col = wc + j * 16 + fr;
                long idx = cTile + (long)row * ldc + col;
                float v = acc[i][j][r];
                if constexpr (EPI == 0) ((float*)Cv)[idx] = v;
                else if constexpr (EPI == 1) ((__hip_bfloat16*)Cv)[idx] = __float2bfloat16(v);
                else if constexpr (EPI == 2) {
                    float gg = 0.5f * v * (1.f + tanhf(0.7978845608f * (v + 0.044715f * v * v * v)));
                    ((__hip_bfloat16*)Cv)[idx] = __float2bfloat16(gg);
                } else ((float*)Cv)[idx] = tanhf(v * (1.f / 30.f)) * 30.f;
            }
}

// ---------------- host ----------------
extern "C" void kernel_launch(void* const* d_in, const int* in_sizes, int n_in,
                              void* d_out, int out_size, void* d_ws, size_t ws_size,
                              hipStream_t stream) {
    const int*   ids    = (const int*)d_in[0];
    const float* embedW = (const float*)d_in[1];
    const float* wq     = (const float*)d_in[2];
    const float* wk     = (const float*)d_in[3];
    const float* wv     = (const float*)d_in[4];
    const float* wo     = (const float*)d_in[5];
    const float* wg     = (const float*)d_in[6];
    const float* wu     = (const float*)d_in[7];
    const float* wd     = (const float*)d_in[8];
    const float* ln_in  = (const float*)d_in[9];
    const float* ln_pa  = (const float*)d_in[10];
    const float* ln_pf  = (const float*)d_in[11];
    const float* ln_pff = (const float*)d_in[12];
    const float* ln_f   = (const float*)d_in[13];
    const float* w_lm   = (const float*)d_in[14];
    float* out = (float*)d_out;

    char* ws = (char*)d_ws;
    size_t off = 0;
    auto alloc = [&](size_t bytes) -> void* {
        size_t o = (off + 255) & ~(size_t)255;
        off = o + bytes;
        return (void*)(ws + o);
    };

    float* h            = (float*)alloc((size_t)S * D * 4);
    __hip_bfloat16* xb  = (__hip_bfloat16*)alloc((size_t)S * D * 2);
    __hip_bfloat16* qkvb = (__hip_bfloat16*)alloc((size_t)S * 4096 * 2); // q|k|v packed
    __hip_bfloat16* vT  = (__hip_bfloat16*)alloc((size_t)NKV * HD * S * 2);
    __hip_bfloat16* ab  = (__hip_bfloat16*)alloc((size_t)S * NH * HD * 2);
    float* tmpf         = (float*)alloc((size_t)S * D * 4);
    __hip_bfloat16* gu  = (__hip_bfloat16*)alloc((size_t)S * 16384 * 2); // gate|up packed
    float* cosb         = (float*)alloc((size_t)S * 128 * 4);
    float* sinb         = (float*)alloc((size_t)S * 128 * 4);
    float* scores       = (float*)alloc((size_t)NH * S * S * 4);
    __hip_bfloat16* probs = (__hip_bfloat16*)alloc((size_t)NH * S * S * 2);

    // packed bf16 weight copies
    const long SLq = 2048L * 2048, SLkv = 1024L * 2048, SLff = 8192L * 2048;
    const long nWlm = (long)VOCAB * D;
    __hip_bfloat16* wqkvb = (__hip_bfloat16*)alloc(4L * 4096 * 2048 * 2);  // [l][4096][2048]
    __hip_bfloat16* wgub  = (__hip_bfloat16*)alloc(4L * 16384 * 2048 * 2); // [l][16384][2048]
    __hip_bfloat16* wob   = (__hip_bfloat16*)alloc(4L * SLq * 2);
    __hip_bfloat16* wdb   = (__hip_bfloat16*)alloc(4L * SLff * 2);
    __hip_bfloat16* wlmb  = (__hip_bfloat16*)alloc(nWlm * 2);
    const bool big = (off <= ws_size);
    (void)in_sizes; (void)n_in; (void)out_size;

    rope_table_kernel<<<dim3(S), dim3(128), 0, stream>>>(cosb, sinb);
    embed_kernel<<<dim3(D / 256, S), dim3(256), 0, stream>>>(ids, embedW, h);

    auto cvt = [&](const float* s, __hip_bfloat16* dp, long n) {
        long n8 = n / 8;
        long want = (n8 + 255) / 256;
        int blocks = (int)(want < 2048 ? want : 2048);
        cvt_bf16_kernel<<<dim3(blocks), dim3(256), 0, stream>>>(s, dp, n8);
    };
    if (big) {
        for (int l = 0; l < NLAYER; ++l) {
            cvt(wq + l * SLq,  wqkvb + (size_t)l * 4096 * 2048,               SLq);
            cvt(wk + l * SLkv, wqkvb + (size_t)l * 4096 * 2048 + 2048L * 2048, SLkv);
            cvt(wv + l * SLkv, wqkvb + (size_t)l * 4096 * 2048 + 3072L * 2048, SLkv);
            cvt(wg + l * SLff, wgub + (size_t)l * 16384 * 2048,               SLff);
            cvt(wu + l * SLff, wgub + (size_t)l * 16384 * 2048 + 8192L * 2048, SLff);
        }
        cvt(wo, wob, 4L * SLq);
        cvt(wd, wdb, 4L * SLff);
        cvt(w_lm, wlmb, nWlm);
    }

    // pipelined weight-GEMM launcher: 1-D grid gx*gy
    auto gemmP = [&](int epi, const __hip_bfloat16* A, const __hip_bfloat16* B, void* C,
                     int K, int lda, int ldb, int ldc, int gx, int gy) {
        dim3 grid(gx * gy, 1, 1);
        switch (epi) {
        case 0: gemm_pipe<0><<<grid, 512, 0, stream>>>(A, B, C, K, lda, ldb, ldc, gx); break;
        case 1: gemm_pipe<1><<<grid, 512, 0, stream>>>(A, B, C, K, lda, ldb, ldc, gx); break;
        case 3: gemm_pipe<3><<<grid, 512, 0, stream>>>(A, B, C, K, lda, ldb, ldc, gx); break;
        default: gemm_pipe<4><<<grid, 512, 0, stream>>>(A, B, C, K, lda, ldb, ldc, gx); break;
        }
    };

    for (int l = 0; l < NLAYER; ++l) {
        int isLocal = (l % 2 == 0) ? 1 : 0;
        rms_bf16_kernel<<<dim3(S), dim3(256), 0, stream>>>(h, ln_in + l * D, xb);
        if (big) {
            // fused q|k|v projection: [S,2048] x [4096,2048]^T -> [S,4096]
            gemmP(1, xb, wqkvb + (size_t)l * 4096 * 2048, qkvb, D, D, D, 4096, 8, 16);
        } else {
            gemm_f32w<1><<<dim3(16, 16), 256, 0, stream>>>(xb, wq + l * SLq, qkvb, D, D, D, 4096);
            gemm_f32w<1><<<dim3(16, 8), 256, 0, stream>>>(xb, wk + l * SLkv, qkvb + 2048, D, D, D, 4096);
            gemm_f32w<1><<<dim3(16, 8), 256, 0, stream>>>(xb, wv + l * SLkv, qkvb + 3072, D, D, D, 4096);
        }
        rope_kernel<<<dim3(S, NH), dim3(128), 0, stream>>>(qkvb, cosb, sinb, 4096);
        rope_kernel<<<dim3(S, NKV), dim3(128), 0, stream>>>(qkvb + 2048, cosb, sinb, 4096);
        transpose_v_kernel<<<dim3(S / 64, HD / 64, NKV), 256, 0, stream>>>(qkvb + 3072, vT, 4096);
        // scores = q @ k^T per head, masked-tile skip
        gemm_bf16<0><<<dim3(256, 1, NH), 256, 0, stream>>>(
            qkvb, qkvb + 2048, scores, HD, 4096, 4096, S,
            (long)HD, (long)HD, (long)S * S, 2, 16, isLocal ? 2 : 1);
        softmax_kernel<<<dim3(S, NH), dim3(256), 0, stream>>>(scores, probs, isLocal);
        // a = probs @ vT, K-range restricted to valid band
        gemm_bf16<1><<<dim3(32, 1, NH), 256, 0, stream>>>(
            probs, vT, ab, S, S, S, NH * HD,
            (long)S * S, (long)HD * S, (long)HD, 2, 16, isLocal ? 4 : 3);
        if (big) {
            gemmP(0, ab, wob + (size_t)l * SLq, tmpf, NH * HD, NH * HD, NH * HD, D, 8, 8);
        } else {
            gemm_f32w<0><<<dim3(16, 16), 256, 0, stream>>>(ab, wo + l * SLq, tmpf, NH * HD, NH * HD, NH * HD, D);
        }
        resid_rms_kernel<<<dim3(S), dim3(256), 0, stream>>>(h, tmpf, ln_pa + l * D);
        rms_bf16_kernel<<<dim3(S), dim3(256), 0, stream>>>(h, ln_pf + l * D, xb);
        if (big) {
            // fused gate|up: [S,2048] x [16384,2048]^T -> [S,16384], gelu on gate half
            gemmP(4, xb, wgub + (size_t)l * 16384 * 2048, gu, D, D, D, 16384, 8, 64);
        } else {
            gemm_f32w<2><<<dim3(16, 64), 256, 0, stream>>>(xb, wg + l * SLff, gu, D, D, D, 16384);
            gemm_f32w<1><<<dim3(16, 64), 256, 0, stream>>>(xb, wu + l * SLff, gu + 8192, D, D, D, 16384);
        }
        mul_gu_kernel<<<dim3((S * FF) / (256 * 8)), 256, 0, stream>>>(gu);
        if (big) {
            gemmP(0, gu, wdb + (size_t)l * SLff, tmpf, FF, 16384, FF, D, 8, 8);
        } else {
            gemm_f32w<0><<<dim3(16, 16), 256, 0, stream>>>(gu, wd + l * SLff, tmpf, FF, 16384, FF, D);
        }
        resid_rms_kernel<<<dim3(S), dim3(256), 0, stream>>>(h, tmpf, ln_pff + l * D);
    }

    rms_bf16_kernel<<<dim3(S), dim3(256), 0, stream>>>(h, ln_f, xb);
    if (big) {
        gemmP(3, xb, wlmb, out, D, D, D, VOCAB, 8, VOCAB / 256);
    } else {
        gemm_f32w<3><<<dim3(16, VOCAB / 128), 256, 0, stream>>>(xb, w_lm, out, D, D, D, VOCAB);
    }
}

// Round 4
// 2707.964 us; speedup vs baseline: 1.9157x; 1.2435x over previous
//
#include <hip/hip_runtime.h>
#include <hip/hip_bf16.h>

typedef __attribute__((ext_vector_type(8))) __bf16 bf16x8;
typedef __attribute__((ext_vector_type(4))) float floatx4;

typedef __attribute__((address_space(1))) const unsigned char kGlb;
typedef __attribute__((address_space(3))) unsigned char kLds;

static constexpr int S = 2048;
static constexpr int D = 2048;
static constexpr int HD = 256;
static constexpr int NH = 8;
static constexpr int NKV = 4;
static constexpr int NLAYER = 4;
static constexpr int VOCAB = 32000;
static constexpr int FF = 8192;
static constexpr int WINDOW = 1024;

// ---------------- block reduction helpers (256 threads = 4 waves) ----------------
__device__ __forceinline__ float blk_sum(float v) {
    __shared__ float sm[4];
    #pragma unroll
    for (int o = 32; o > 0; o >>= 1) v += __shfl_down(v, o, 64);
    int lane = threadIdx.x & 63, w = threadIdx.x >> 6;
    __syncthreads();
    if (lane == 0) sm[w] = v;
    __syncthreads();
    return sm[0] + sm[1] + sm[2] + sm[3];
}

__device__ __forceinline__ float blk_max(float v) {
    __shared__ float sm[4];
    #pragma unroll
    for (int o = 32; o > 0; o >>= 1) v = fmaxf(v, __shfl_down(v, o, 64));
    int lane = threadIdx.x & 63, w = threadIdx.x >> 6;
    __syncthreads();
    if (lane == 0) sm[w] = v;
    __syncthreads();
    return fmaxf(fmaxf(sm[0], sm[1]), fmaxf(sm[2], sm[3]));
}

// ---------------- elementwise kernels ----------------
__global__ void embed_kernel(const int* __restrict__ ids, const float* __restrict__ E,
                             float* __restrict__ h) {
    int d = blockIdx.x * 256 + threadIdx.x;
    int s = blockIdx.y;
    h[(long)s * D + d] = E[(long)ids[s] * D + d] * 45.25483399593904f; // sqrt(2048)
}

__global__ void rope_table_kernel(float* __restrict__ c, float* __restrict__ sn) {
    int i = threadIdx.x;   // 0..127
    int p = blockIdx.x;    // 0..S-1
    float inv = powf(10000.f, -(float)i / 128.f);
    float a = (float)p * inv;
    c[p * 128 + i] = cosf(a);
    sn[p * 128 + i] = sinf(a);
}

// fp32 -> bf16 conversion (grid-stride, 8 elems/thread/iter)
__global__ void cvt_bf16_kernel(const float* __restrict__ src, __hip_bfloat16* __restrict__ dst,
                                long n8) {
    long stride = (long)gridDim.x * 256;
    for (long i = (long)blockIdx.x * 256 + threadIdx.x; i < n8; i += stride) {
        long o = i * 8;
        float4 a = *(const float4*)(src + o);
        float4 b = *(const float4*)(src + o + 4);
        __hip_bfloat16 h8[8] = {
            __float2bfloat16(a.x), __float2bfloat16(a.y),
            __float2bfloat16(a.z), __float2bfloat16(a.w),
            __float2bfloat16(b.x), __float2bfloat16(b.y),
            __float2bfloat16(b.z), __float2bfloat16(b.w)};
        *(uint4*)(dst + o) = *(const uint4*)h8;
    }
}

// x = rms(h, w) -> bf16
__global__ void rms_bf16_kernel(const float* __restrict__ h, const float* __restrict__ w,
                                __hip_bfloat16* __restrict__ o) {
    int s = blockIdx.x;
    const float* row = h + (long)s * D;
    float vals[8], ss = 0.f;
    #pragma unroll
    for (int t = 0; t < 8; ++t) {
        int j = t * 256 + threadIdx.x;
        float v = row[j]; vals[t] = v; ss += v * v;
    }
    ss = blk_sum(ss);
    float r = rsqrtf(ss * (1.f / D) + 1e-6f);
    #pragma unroll
    for (int t = 0; t < 8; ++t) {
        int j = t * 256 + threadIdx.x;
        o[(long)s * D + j] = __float2bfloat16(vals[t] * r * (1.f + w[j]));
    }
}

// h += rms(t, w)
__global__ void resid_rms_kernel(float* __restrict__ h, const float* __restrict__ tt,
                                 const float* __restrict__ w) {
    int s = blockIdx.x;
    const float* row = tt + (long)s * D;
    float* hr = h + (long)s * D;
    float vals[8], ss = 0.f;
    #pragma unroll
    for (int t = 0; t < 8; ++t) {
        int j = t * 256 + threadIdx.x;
        float v = row[j]; vals[t] = v; ss += v * v;
    }
    ss = blk_sum(ss);
    float r = rsqrtf(ss * (1.f / D) + 1e-6f);
    #pragma unroll
    for (int t = 0; t < 8; ++t) {
        int j = t * 256 + threadIdx.x;
        hr[j] += vals[t] * r * (1.f + w[j]);
    }
}

// in-place RoPE on rows with stride ldx; head offset hh*HD; 128 threads per (s, head)
__global__ void rope_kernel(__hip_bfloat16* __restrict__ x, const float* __restrict__ cb,
                            const float* __restrict__ sb, int ldx) {
    int s = blockIdx.x, hh = blockIdx.y, i = threadIdx.x; // i in 0..127
    __hip_bfloat16* p = x + (long)s * ldx + hh * HD;
    float x1 = __bfloat162float(p[i]);
    float x2 = __bfloat162float(p[128 + i]);
    float c = cb[s * 128 + i], sn = sb[s * 128 + i];
    p[i]       = __float2bfloat16(x1 * c - x2 * sn);
    p[128 + i] = __float2bfloat16(x1 * sn + x2 * c);
}

// v rows (stride ldv, base already offset to v region) -> vT (NKV, HD, S) bf16
__global__ void transpose_v_kernel(const __hip_bfloat16* __restrict__ v,
                                   __hip_bfloat16* __restrict__ vt, int ldv) {
    __shared__ ushort tile[64][65];
    int s0 = blockIdx.x * 64, d0 = blockIdx.y * 64, kv = blockIdx.z;
    const ushort* vin = (const ushort*)v;
    ushort* vout = (ushort*)vt;
    #pragma unroll
    for (int it = 0; it < 4; ++it) {
        int slot = it * 256 + threadIdx.x;
        int r = slot >> 4, c4 = (slot & 15) << 2;
        ushort4 x = *(const ushort4*)(vin + (long)(s0 + r) * ldv + kv * HD + d0 + c4);
        tile[r][c4] = x.x; tile[r][c4 + 1] = x.y; tile[r][c4 + 2] = x.z; tile[r][c4 + 3] = x.w;
    }
    __syncthreads();
    #pragma unroll
    for (int it = 0; it < 4; ++it) {
        int slot = it * 256 + threadIdx.x;
        int rr = slot >> 4, c4 = (slot & 15) << 2;
        ushort4 y;
        y.x = tile[c4][rr]; y.y = tile[c4 + 1][rr]; y.z = tile[c4 + 2][rr]; y.w = tile[c4 + 3][rr];
        *(ushort4*)(vout + (long)kv * HD * S + (long)(d0 + rr) * S + s0 + c4) = y;
    }
}

// scores (NH,S,S) f32 -> probs bf16, with scale, tanh softcap, mask, softmax.
__global__ void softmax_kernel(const float* __restrict__ sc, __hip_bfloat16* __restrict__ pr,
                               int isLocal) {
    int i = blockIdx.x, hh = blockIdx.y;
    const float* row = sc + ((long)hh * S + i) * S;
    __hip_bfloat16* orow = pr + ((long)hh * S + i) * S;
    int lo = isLocal ? max(0, i - (WINDOW - 1)) : 0;
    float vals[8];
    float m = -3.0e38f;
    #pragma unroll
    for (int t = 0; t < 8; ++t) {
        int j = t * 256 + threadIdx.x;
        bool chunkAny = (t * 256 <= i) && (t * 256 + 255 >= lo);
        if (chunkAny) {
            bool valid = (j <= i) && (j >= lo);
            float v = tanhf(row[j] * (0.0625f / 50.f)) * 50.f; // SCALE=1/16, softcap 50
            vals[t] = valid ? v : -3.0e38f;
            m = fmaxf(m, vals[t]);
        } else {
            vals[t] = -3.0e38f;
        }
    }
    m = blk_max(m);
    float ps[8], ssum = 0.f;
    #pragma unroll
    for (int t = 0; t < 8; ++t) {
        float p = (vals[t] > -1.0e38f) ? __expf(vals[t] - m) : 0.f;
        ps[t] = p; ssum += p;
    }
    ssum = blk_sum(ssum);
    float inv = 1.f / ssum;
    #pragma unroll
    for (int t = 0; t < 8; ++t) {
        int j = t * 256 + threadIdx.x;
        orow[j] = __float2bfloat16(ps[t] * inv);
    }
}

// gate half *= up half, packed gu[S][16384]
__global__ void mul_gu_kernel(__hip_bfloat16* __restrict__ gu) {
    long idx = ((long)blockIdx.x * 256 + threadIdx.x) * 8;
    long s = idx >> 13;
    long f = idx & 8191;
    __hip_bfloat16* gp = gu + s * 16384 + f;
    const __hip_bfloat16* up = gu + s * 16384 + 8192 + f;
    uint4 gv = *(const uint4*)gp;
    uint4 uv = *(const uint4*)up;
    const __hip_bfloat16* gb = (const __hip_bfloat16*)&gv;
    const __hip_bfloat16* ub = (const __hip_bfloat16*)&uv;
    __hip_bfloat16 o[8];
    #pragma unroll
    for (int j = 0; j < 8; ++j)
        o[j] = __float2bfloat16(__bfloat162float(gb[j]) * __bfloat162float(ub[j]));
    *(uint4*)gp = *(const uint4*)o;
}

// ---------------- generic pipelined GEMM: C[M,N] = A[M,K] * B[N,K]^T, bf16 ----------------
// Tile BM=WM*MI*16 x BN=WN*NI*16, BK=32, threads T=WM*WN*64 (BM==BN==T/2 required by staging).
// 4 LDS buffers, depth-3 prefetch, 2 sub-phases/K-tile, counted vmcnt(8), setprio around MFMA,
// both-sides XOR swizzle (chunk ^= (row>>1)&3), XCD-chunked 1-D grid remap (nwg % 8 == 0).
// EPI: 0=f32, 1=bf16, 3=tanh(x/30)*30->f32, 4=gelu if global col<8192 else plain ->bf16
// kMode: 0 none; 1 causal score-tile skip; 2 local score-tile skip; 3 causal PV K-range; 4 local PV K-range
template<int EPI, int WM, int WN, int MI, int NI>
__global__ __launch_bounds__(WM*WN*64, 2) void gemm_pipe(
    const __hip_bfloat16* __restrict__ A, const __hip_bfloat16* __restrict__ B,
    void* __restrict__ Cv, int K, int lda, int ldb, int ldc,
    long aBatch, long bBatch, long cBatch, int bzDiv, int gx, int kMode) {
    constexpr int T  = WM * WN * 64;
    constexpr int BM = WM * MI * 16;
    constexpr int BN = WN * NI * 16;
    constexpr int AE = BM * 32;   // elems per A-buffer
    constexpr int BE = BN * 32;
    __shared__ __hip_bfloat16 lds[4][AE + BE];

    const int tid = threadIdx.x;
    const int nwg = gridDim.x;
    const int orig = blockIdx.x;
    const int wgid = (orig & 7) * (nwg >> 3) + (orig >> 3);
    const int bx = wgid % gx, by = wgid / gx;
    const int bz = blockIdx.z;

    int kstart = 0, kend = K;
    if (kMode == 1) { if (by > bx) return; }
    else if (kMode == 2) { if (by > bx || bx - by >= 9) return; }
    else if (kMode == 3) { kend = min(K, (bx + 1) * BM); }
    else if (kMode == 4) { kend = min(K, (bx + 1) * BM); kstart = max(0, (bx - 1024 / BM) * BM); }

    const __hip_bfloat16* Ab = A + (long)bz * aBatch + (long)bx * BM * lda;
    const __hip_bfloat16* Bb = B + (long)(bz / bzDiv) * bBatch + (long)by * BN * ldb;

    const int w = tid >> 6, l = tid & 63;
    const int wm = w / WN, wn = w % WN;
    const int wrow = wm * MI * 16, wcol = wn * NI * 16;
    const int fr = l & 15, g = l >> 4;
    const int sR = tid >> 2;      // staging base row (+ i*T/4)
    const int sc = tid & 3;       // staging 16B chunk in 64B row

    floatx4 acc[MI][NI] = {};
    bf16x8 bfv[NI];
    bf16x8 af[MI / 2];

    auto stageA = [&](int t, int buf) {
        const int k0 = kstart + t * 32;
        #pragma unroll
        for (int i = 0; i < 2; ++i) {
            int row = sR + i * (T / 4);
            int scol = ((sc ^ ((row >> 1) & 3)) << 3);
            __builtin_amdgcn_global_load_lds(
                (kGlb*)(Ab + (long)row * lda + k0 + scol),
                (kLds*)(&lds[buf][0] + tid * 8 + i * (T * 8)), 16, 0, 0);
        }
    };
    auto stageB = [&](int t, int buf) {
        const int k0 = kstart + t * 32;
        #pragma unroll
        for (int i = 0; i < 2; ++i) {
            int row = sR + i * (T / 4);
            int scol = ((sc ^ ((row >> 1) & 3)) << 3);
            __builtin_amdgcn_global_load_lds(
                (kGlb*)(Bb + (long)row * ldb + k0 + scol),
                (kLds*)(&lds[buf][AE] + tid * 8 + i * (T * 8)), 16, 0, 0);
        }
    };

    auto phase0 = [&](int buf, int t3, bool doStage) {
        const char* AsB = (const char*)&lds[buf][0];
        const char* BsB = (const char*)&lds[buf][AE];
        #pragma unroll
        for (int mi = 0; mi < MI / 2; ++mi) {
            int ra = wrow + mi * 16 + fr;
            af[mi] = *(const bf16x8*)(AsB + ra * 64 + ((g ^ ((ra >> 1) & 3)) << 4));
        }
        #pragma unroll
        for (int ni = 0; ni < NI; ++ni) {
            int rb = wcol + ni * 16 + fr;
            bfv[ni] = *(const bf16x8*)(BsB + rb * 64 + ((g ^ ((rb >> 1) & 3)) << 4));
        }
        if (doStage) stageA(t3, t3 & 3);
        __builtin_amdgcn_s_barrier();
        asm volatile("s_waitcnt lgkmcnt(0)" ::: "memory");
        __builtin_amdgcn_sched_barrier(0);
        __builtin_amdgcn_s_setprio(1);
        #pragma unroll
        for (int mi = 0; mi < MI / 2; ++mi)
            #pragma unroll
            for (int ni = 0; ni < NI; ++ni)
                acc[mi][ni] = __builtin_amdgcn_mfma_f32_16x16x32_bf16(af[mi], bfv[ni], acc[mi][ni], 0, 0, 0);
        __builtin_amdgcn_s_setprio(0);
        __builtin_amdgcn_sched_barrier(0);
        __builtin_amdgcn_s_barrier();
    };

    auto phase1 = [&](int buf, int t3, bool doStage, int vm) {
        const char* AsB = (const char*)&lds[buf][0];
        #pragma unroll
        for (int mi = 0; mi < MI / 2; ++mi) {
            int ra = wrow + (MI / 2 + mi) * 16 + fr;
            af[mi] = *(const bf16x8*)(AsB + ra * 64 + ((g ^ ((ra >> 1) & 3)) << 4));
        }
        if (doStage) stageB(t3, t3 & 3);
        if (vm == 8)      asm volatile("s_waitcnt vmcnt(8)" ::: "memory");
        else if (vm == 4) asm volatile("s_waitcnt vmcnt(4)" ::: "memory");
        else if (vm == 0) asm volatile("s_waitcnt vmcnt(0)" ::: "memory");
        __builtin_amdgcn_s_barrier();
        asm volatile("s_waitcnt lgkmcnt(0)" ::: "memory");
        __builtin_amdgcn_sched_barrier(0);
        __builtin_amdgcn_s_setprio(1);
        #pragma unroll
        for (int mi = 0; mi < MI / 2; ++mi)
            #pragma unroll
            for (int ni = 0; ni < NI; ++ni)
                acc[MI / 2 + mi][ni] = __builtin_amdgcn_mfma_f32_16x16x32_bf16(af[mi], bfv[ni], acc[MI / 2 + mi][ni], 0, 0, 0);
        __builtin_amdgcn_s_setprio(0);
        __builtin_amdgcn_sched_barrier(0);
        __builtin_amdgcn_s_barrier();
    };

    const int nt = (kend - kstart) >> 5;   // >= 4 at all call sites
    stageA(0, 0); stageB(0, 0);
    stageA(1, 1); stageB(1, 1);
    stageA(2, 2); stageB(2, 2);
    asm volatile("s_waitcnt vmcnt(8)" ::: "memory");
    __builtin_amdgcn_s_barrier();

    for (int t = 0; t < nt - 3; ++t) {
        const int b = t & 3;
        phase0(b, t + 3, true);
        phase1(b, t + 3, true, 8);
    }
    phase0((nt - 3) & 3, 0, false); phase1((nt - 3) & 3, 0, false, 4);
    phase0((nt - 2) & 3, 0, false); phase1((nt - 2) & 3, 0, false, 0);
    phase0((nt - 1) & 3, 0, false); phase1((nt - 1) & 3, 0, false, -1);

    const long cBase = (long)bz * cBatch + (long)bx * BM * ldc + (long)by * BN;
    const int rg = (l >> 4) * 4;
    #pragma unroll
    for (int mi = 0; mi < MI; ++mi) {
        #pragma unroll
        for (int ni = 0; ni < NI; ++ni) {
            #pragma unroll
            for (int r = 0; r < 4; ++r) {
                int row = wrow + mi * 16 + rg + r;
                int col = wcol + ni * 16 + fr;
                long idx = cBase + (long)row * ldc + col;
                float v = acc[mi][ni][r];
                if constexpr (EPI == 0) {
                    ((float*)Cv)[idx] = v;
                } else if constexpr (EPI == 1) {
                    ((__hip_bfloat16*)Cv)[idx] = __float2bfloat16(v);
                } else if constexpr (EPI == 3) {
                    ((float*)Cv)[idx] = tanhf(v * (1.f / 30.f)) * 30.f;
                } else { // EPI 4: fused gate|up epilogue
                    int colg = by * BN + col;
                    float o = v;
                    if (colg < 8192)
                        o = 0.5f * v * (1.f + tanhf(0.7978845608f * (v + 0.044715f * v * v * v)));
                    ((__hip_bfloat16*)Cv)[idx] = __float2bfloat16(o);
                }
            }
        }
    }
}

// ---------------- fallback GEMMs (used only if ws too small) ----------------
template<int EPI>
__global__ __launch_bounds__(256) void gemm_bf16(
    const __hip_bfloat16* __restrict__ A, const __hip_bfloat16* __restrict__ B,
    void* __restrict__ Cv, int K, int lda, int ldb, int ldc,
    long aBatch, long bBatch, long cBatch, int bzDiv, int gx, int kMode) {
    __shared__ __hip_bfloat16 As[128 * 32];
    __shared__ __hip_bfloat16 Bs[128 * 32];
    const int tid = threadIdx.x;
    const int nwg = gridDim.x;
    const int orig = blockIdx.x;
    const int wgid = (orig & 7) * (nwg >> 3) + (orig >> 3);
    const int bx = wgid % gx, by = wgid / gx;
    const int bz = blockIdx.z;

    int kstart = 0, kend = K;
    if (kMode == 1) { if (by > bx) return; }
    else if (kMode == 2) { if (by > bx || bx - by >= 9) return; }
    else if (kMode == 3) { kend = min(K, (bx + 1) * 128); }
    else if (kMode == 4) { kend = min(K, (bx + 1) * 128); kstart = max(0, (bx - 8) * 128); }

    const __hip_bfloat16* Ab = A + (long)bz * aBatch + (long)bx * 128 * lda;
    const __hip_bfloat16* Bb = B + (long)(bz / bzDiv) * bBatch + (long)by * 128 * ldb;

    const int w = tid >> 6, l = tid & 63;
    int srow[2], scsrc[2], sdst[2];
    #pragma unroll
    for (int i = 0; i < 2; ++i) {
        int o = w * 2048 + i * 1024 + l * 16;
        int row = o >> 6;
        int chunk = (o >> 4) & 3;
        srow[i]  = row;
        scsrc[i] = (chunk ^ ((row >> 1) & 3)) * 8;
        sdst[i]  = w * 1024 + i * 512;
    }
    const int wr = (w >> 1) * 64, wc = (w & 1) * 64;
    const int fr = l & 15;
    const int g  = l >> 4;
    floatx4 acc[4][4] = {};
    for (int k0 = kstart; k0 < kend; k0 += 32) {
        __syncthreads();
        #pragma unroll
        for (int i = 0; i < 2; ++i) {
            __builtin_amdgcn_global_load_lds(
                (kGlb*)(Ab + (long)srow[i] * lda + k0 + scsrc[i]),
                (kLds*)(As + sdst[i]), 16, 0, 0);
            __builtin_amdgcn_global_load_lds(
                (kGlb*)(Bb + (long)srow[i] * ldb + k0 + scsrc[i]),
                (kLds*)(Bs + sdst[i]), 16, 0, 0);
        }
        __syncthreads();
        bf16x8 af[4], bfr[4];
        const char* AsB = (const char*)As;
        const char* BsB = (const char*)Bs;
        #pragma unroll
        for (int i = 0; i < 4; ++i) {
            int ra = wr + i * 16 + fr;
            af[i] = *(const bf16x8*)(AsB + ra * 64 + (((g ^ ((ra >> 1) & 3))) << 4));
        }
        #pragma unroll
        for (int j = 0; j < 4; ++j) {
            int rb = wc + j * 16 + fr;
            bfr[j] = *(const bf16x8*)(BsB + rb * 64 + (((g ^ ((rb >> 1) & 3))) << 4));
        }
        #pragma unroll
        for (int i = 0; i < 4; ++i)
            #pragma unroll
            for (int j = 0; j < 4; ++j)
                acc[i][j] = __builtin_amdgcn_mfma_f32_16x16x32_bf16(af[i], bfr[j], acc[i][j], 0, 0, 0);
    }
    const long cTile = (long)bz * cBatch + (long)bx * 128 * ldc + (long)by * 128;
    const int rg = (l >> 4) * 4;
    #pragma unroll
    for (int i = 0; i < 4; ++i)
        #pragma unroll
        for (int j = 0; j < 4; ++j)
            #pragma unroll
            for (int r = 0; r < 4; ++r) {
                int row = wr + i * 16 + rg + r;
                int col = wc + j * 16 + fr;
                long idx = cTile + (long)row * ldc + col;
                float v = acc[i][j][r];
                if constexpr (EPI == 0) ((float*)Cv)[idx] = v;
                else ((__hip_bfloat16*)Cv)[idx] = __float2bfloat16(v);
            }
}

template<int EPI>
__global__ __launch_bounds__(256) void gemm_f32w(
    const __hip_bfloat16* __restrict__ A, const float* __restrict__ Bv,
    void* __restrict__ Cv, int K, int lda, int ldb, int ldc) {
    __shared__ __hip_bfloat16 As[128][32];
    __shared__ __hip_bfloat16 Bs[128][32];
    const int tid = threadIdx.x;
    const __hip_bfloat16* Ab = A + (long)blockIdx.x * 128 * lda;
    const float* Bb = Bv + (long)blockIdx.y * 128 * ldb;
    const int wid = tid >> 6, lane = tid & 63;
    const int wr = (wid >> 1) * 64, wc = (wid & 1) * 64;
    const int fr = lane & 15;
    const int kb = (lane >> 4) * 8;
    floatx4 acc[4][4] = {};
    for (int k0 = 0; k0 < K; k0 += 32) {
        __syncthreads();
        #pragma unroll
        for (int it = 0; it < 2; ++it) {
            int slot = tid + it * 256;
            int r = slot >> 2, c8 = (slot & 3) * 8;
            *reinterpret_cast<uint4*>(&As[r][c8]) =
                *reinterpret_cast<const uint4*>(Ab + (long)r * lda + k0 + c8);
        }
        #pragma unroll
        for (int it = 0; it < 4; ++it) {
            int slot = tid + it * 256;
            int r = slot >> 3, c4 = (slot & 7) * 4;
            float4 f = *reinterpret_cast<const float4*>(Bb + (long)r * ldb + k0 + c4);
            __hip_bfloat16 t4[4] = {__float2bfloat16(f.x), __float2bfloat16(f.y),
                                    __float2bfloat16(f.z), __float2bfloat16(f.w)};
            *reinterpret_cast<ushort4*>(&Bs[r][c4]) = *reinterpret_cast<const ushort4*>(t4);
        }
        __syncthreads();
        bf16x8 af[4], bfr[4];
        #pragma unroll
        for (int i = 0; i < 4; ++i)
            af[i] = *reinterpret_cast<const bf16x8*>(&As[wr + i * 16 + fr][kb]);
        #pragma unroll
        for (int j = 0; j < 4; ++j)
            bfr[j] = *reinterpret_cast<const bf16x8*>(&Bs[wc + j * 16 + fr][kb]);
        #pragma unroll
        for (int i = 0; i < 4; ++i)
            #pragma unroll
            for (int j = 0; j < 4; ++j)
                acc[i][j] = __builtin_amdgcn_mfma_f32_16x16x32_bf16(af[i], bfr[j], acc[i][j], 0, 0, 0);
    }
    const long cTile = (long)blockIdx.x * 128 * ldc + (long)blockIdx.y * 128;
    const int rg = (lane >> 4) * 4;
    #pragma unroll
    for (int i = 0; i < 4; ++i)
        #pragma unroll
        for (int j = 0; j < 4; ++j)
            #pragma unroll
            for (int r = 0; r < 4; ++r) {
                int row = wr + i * 16 + rg + r;
                int col = wc + j * 16 + fr;
                long idx = cTile + (long)row * ldc + col;
                float v = acc[i][j][r];
                if constexpr (EPI == 0) ((float*)Cv)[idx] = v;
                else if constexpr (EPI == 1) ((__hip_bfloat16*)Cv)[idx] = __float2bfloat16(v);
                else if constexpr (EPI == 2) {
                    float gg = 0.5f * v * (1.f + tanhf(0.7978845608f * (v + 0.044715f * v * v * v)));
                    ((__hip_bfloat16*)Cv)[idx] = __float2bfloat16(gg);
                } else ((float*)Cv)[idx] = tanhf(v * (1.f / 30.f)) * 30.f;
            }
}

// ---------------- host ----------------
extern "C" void kernel_launch(void* const* d_in, const int* in_sizes, int n_in,
                              void* d_out, int out_size, void* d_ws, size_t ws_size,
                              hipStream_t stream) {
    const int*   ids    = (const int*)d_in[0];
    const float* embedW = (const float*)d_in[1];
    const float* wq     = (const float*)d_in[2];
    const float* wk     = (const float*)d_in[3];
    const float* wv     = (const float*)d_in[4];
    const float* wo     = (const float*)d_in[5];
    const float* wg     = (const float*)d_in[6];
    const float* wu     = (const float*)d_in[7];
    const float* wd     = (const float*)d_in[8];
    const float* ln_in  = (const float*)d_in[9];
    const float* ln_pa  = (const float*)d_in[10];
    const float* ln_pf  = (const float*)d_in[11];
    const float* ln_pff = (const float*)d_in[12];
    const float* ln_f   = (const float*)d_in[13];
    const float* w_lm   = (const float*)d_in[14];
    float* out = (float*)d_out;

    char* ws = (char*)d_ws;
    size_t off = 0;
    auto alloc = [&](size_t bytes) -> void* {
        size_t o = (off + 255) & ~(size_t)255;
        off = o + bytes;
        return (void*)(ws + o);
    };

    float* h            = (float*)alloc((size_t)S * D * 4);
    __hip_bfloat16* xb  = (__hip_bfloat16*)alloc((size_t)S * D * 2);
    __hip_bfloat16* qkvb = (__hip_bfloat16*)alloc((size_t)S * 4096 * 2); // q|k|v packed
    __hip_bfloat16* vT  = (__hip_bfloat16*)alloc((size_t)NKV * HD * S * 2);
    __hip_bfloat16* ab  = (__hip_bfloat16*)alloc((size_t)S * NH * HD * 2);
    float* tmpf         = (float*)alloc((size_t)S * D * 4);
    __hip_bfloat16* gu  = (__hip_bfloat16*)alloc((size_t)S * 16384 * 2); // gate|up packed
    float* cosb         = (float*)alloc((size_t)S * 128 * 4);
    float* sinb         = (float*)alloc((size_t)S * 128 * 4);
    float* scores       = (float*)alloc((size_t)NH * S * S * 4);
    __hip_bfloat16* probs = (__hip_bfloat16*)alloc((size_t)NH * S * S * 2);

    const long SLq = 2048L * 2048, SLkv = 1024L * 2048, SLff = 8192L * 2048;
    const long nWlm = (long)VOCAB * D;
    __hip_bfloat16* wqkvb = (__hip_bfloat16*)alloc(4L * 4096 * 2048 * 2);
    __hip_bfloat16* wgub  = (__hip_bfloat16*)alloc(4L * 16384 * 2048 * 2);
    __hip_bfloat16* wob   = (__hip_bfloat16*)alloc(4L * SLq * 2);
    __hip_bfloat16* wdb   = (__hip_bfloat16*)alloc(4L * SLff * 2);
    __hip_bfloat16* wlmb  = (__hip_bfloat16*)alloc(nWlm * 2);
    const bool big = (off <= ws_size);
    (void)in_sizes; (void)n_in; (void)out_size;

    rope_table_kernel<<<dim3(S), dim3(128), 0, stream>>>(cosb, sinb);
    embed_kernel<<<dim3(D / 256, S), dim3(256), 0, stream>>>(ids, embedW, h);

    auto cvt = [&](const float* s, __hip_bfloat16* dp, long n) {
        long n8 = n / 8;
        long want = (n8 + 255) / 256;
        int blocks = (int)(want < 2048 ? want : 2048);
        cvt_bf16_kernel<<<dim3(blocks), dim3(256), 0, stream>>>(s, dp, n8);
    };
    if (big) {
        for (int l = 0; l < NLAYER; ++l) {
            cvt(wq + l * SLq,  wqkvb + (size_t)l * 4096 * 2048,                SLq);
            cvt(wk + l * SLkv, wqkvb + (size_t)l * 4096 * 2048 + 2048L * 2048, SLkv);
            cvt(wv + l * SLkv, wqkvb + (size_t)l * 4096 * 2048 + 3072L * 2048, SLkv);
            cvt(wg + l * SLff, wgub + (size_t)l * 16384 * 2048,                SLff);
            cvt(wu + l * SLff, wgub + (size_t)l * 16384 * 2048 + 8192L * 2048, SLff);
        }
        cvt(wo, wob, 4L * SLq);
        cvt(wd, wdb, 4L * SLff);
        cvt(w_lm, wlmb, nWlm);
    }

    // pipe launchers: p256 = 256x256 tile (512 thr), p128 = 128x128 tile (256 thr)
    auto p256 = [&](int epi, const __hip_bfloat16* A, const __hip_bfloat16* B, void* C,
                    int K, int lda, int ldb, int ldc, int gx, int gy) {
        dim3 grid(gx * gy, 1, 1);
        switch (epi) {
        case 3: gemm_pipe<3, 2, 4, 8, 4><<<grid, 512, 0, stream>>>(A, B, C, K, lda, ldb, ldc, 0, 0, 0, 1, gx, 0); break;
        default: gemm_pipe<4, 2, 4, 8, 4><<<grid, 512, 0, stream>>>(A, B, C, K, lda, ldb, ldc, 0, 0, 0, 1, gx, 0); break;
        }
    };
    auto p128 = [&](int epi, const __hip_bfloat16* A, const __hip_bfloat16* B, void* C,
                    int K, int lda, int ldb, int ldc, int gx, int gy, int gz,
                    long aB, long bB, long cB, int bzDiv, int kMode) {
        dim3 grid(gx * gy, 1, gz);
        switch (epi) {
        case 0: gemm_pipe<0, 2, 2, 4, 4><<<grid, 256, 0, stream>>>(A, B, C, K, lda, ldb, ldc, aB, bB, cB, bzDiv, gx, kMode); break;
        default: gemm_pipe<1, 2, 2, 4, 4><<<grid, 256, 0, stream>>>(A, B, C, K, lda, ldb, ldc, aB, bB, cB, bzDiv, gx, kMode); break;
        }
    };

    for (int l = 0; l < NLAYER; ++l) {
        int isLocal = (l % 2 == 0) ? 1 : 0;
        rms_bf16_kernel<<<dim3(S), dim3(256), 0, stream>>>(h, ln_in + l * D, xb);
        if (big) {
            // fused q|k|v projection: [S,2048] x [4096,2048]^T -> [S,4096]
            p128(1, xb, wqkvb + (size_t)l * 4096 * 2048, qkvb, D, D, D, 4096, 16, 32, 1, 0, 0, 0, 1, 0);
        } else {
            gemm_f32w<1><<<dim3(16, 16), 256, 0, stream>>>(xb, wq + l * SLq, qkvb, D, D, D, 4096);
            gemm_f32w<1><<<dim3(16, 8), 256, 0, stream>>>(xb, wk + l * SLkv, qkvb + 2048, D, D, D, 4096);
            gemm_f32w<1><<<dim3(16, 8), 256, 0, stream>>>(xb, wv + l * SLkv, qkvb + 3072, D, D, D, 4096);
        }
        rope_kernel<<<dim3(S, NH), dim3(128), 0, stream>>>(qkvb, cosb, sinb, 4096);
        rope_kernel<<<dim3(S, NKV), dim3(128), 0, stream>>>(qkvb + 2048, cosb, sinb, 4096);
        transpose_v_kernel<<<dim3(S / 64, HD / 64, NKV), 256, 0, stream>>>(qkvb + 3072, vT, 4096);
        // scores = q @ k^T per head, masked-tile skip
        if (big) {
            p128(0, qkvb, qkvb + 2048, scores, HD, 4096, 4096, S, 16, 16, NH,
                 (long)HD, (long)HD, (long)S * S, 2, isLocal ? 2 : 1);
        } else {
            gemm_bf16<0><<<dim3(256, 1, NH), 256, 0, stream>>>(
                qkvb, qkvb + 2048, scores, HD, 4096, 4096, S,
                (long)HD, (long)HD, (long)S * S, 2, 16, isLocal ? 2 : 1);
        }
        softmax_kernel<<<dim3(S, NH), dim3(256), 0, stream>>>(scores, probs, isLocal);
        // a = probs @ vT, K-range restricted to valid band
        if (big) {
            p128(1, probs, vT, ab, S, S, S, NH * HD, 16, 2, NH,
                 (long)S * S, (long)HD * S, (long)HD, 2, isLocal ? 4 : 3);
        } else {
            gemm_bf16<1><<<dim3(32, 1, NH), 256, 0, stream>>>(
                probs, vT, ab, S, S, S, NH * HD,
                (long)S * S, (long)HD * S, (long)HD, 2, 16, isLocal ? 4 : 3);
        }
        if (big) {
            p128(0, ab, wob + (size_t)l * SLq, tmpf, NH * HD, NH * HD, NH * HD, D, 16, 16, 1, 0, 0, 0, 1, 0);
        } else {
            gemm_f32w<0><<<dim3(16, 16), 256, 0, stream>>>(ab, wo + l * SLq, tmpf, NH * HD, NH * HD, NH * HD, D);
        }
        resid_rms_kernel<<<dim3(S), dim3(256), 0, stream>>>(h, tmpf, ln_pa + l * D);
        rms_bf16_kernel<<<dim3(S), dim3(256), 0, stream>>>(h, ln_pf + l * D, xb);
        if (big) {
            // fused gate|up: [S,2048] x [16384,2048]^T -> [S,16384], gelu on gate half
            p256(4, xb, wgub + (size_t)l * 16384 * 2048, gu, D, D, D, 16384, 8, 64);
        } else {
            gemm_f32w<2><<<dim3(16, 64), 256, 0, stream>>>(xb, wg + l * SLff, gu, D, D, D, 16384);
            gemm_f32w<1><<<dim3(16, 64), 256, 0, stream>>>(xb, wu + l * SLff, gu + 8192, D, D, D, 16384);
        }
        mul_gu_kernel<<<dim3((S * FF) / (256 * 8)), 256, 0, stream>>>(gu);
        if (big) {
            p128(0, gu, wdb + (size_t)l * SLff, tmpf, FF, 16384, FF, D, 16, 16, 1, 0, 0, 0, 1, 0);
        } else {
            gemm_f32w<0><<<dim3(16, 16), 256, 0, stream>>>(gu, wd + l * SLff, tmpf, FF, 16384, FF, D);
        }
        resid_rms_kernel<<<dim3(S), dim3(256), 0, stream>>>(h, tmpf, ln_pff + l * D);
    }

    rms_bf16_kernel<<<dim3(S), dim3(256), 0, stream>>>(h, ln_f, xb);
    if (big) {
        p256(3, xb, wlmb, out, D, D, D, VOCAB, 8, VOCAB / 256);
    } else {
        gemm_f32w<3><<<dim3(16, VOCAB / 128), 256, 0, stream>>>(xb, w_lm, out, D, D, D, VOCAB);
    }
}